// Round 1
// baseline (3535.698 us; speedup 1.0000x reference)
//
#include <hip/hip_runtime.h>
#include <cstdint>

#define NN 50000
#define EE 800000
#define DIN 128
#define DD 256
#define DOUT 64
#define NLAYERS 3
#define LN_EPS 1e-5f

__device__ __forceinline__ float waveSum(float v) {
#pragma unroll
  for (int m = 1; m < 64; m <<= 1) v += __shfl_xor(v, m, 64);
  return v;
}

// h = relu(x @ W_enc + b_enc)   [N,128]@[128,256]
__global__ __launch_bounds__(256) void k_encoder(const float* __restrict__ x,
                                                 const float* __restrict__ W,
                                                 const float* __restrict__ b,
                                                 float* __restrict__ h) {
  __shared__ float xs[8][DIN];
  const int tid = threadIdx.x;
  const int row0 = blockIdx.x * 8;
  {
    int idx = tid * 4;
    int r = idx >> 7, c = idx & 127;
    int row = row0 + r;
    float4 v = make_float4(0.f, 0.f, 0.f, 0.f);
    if (row < NN) v = *(const float4*)(x + (size_t)row * DIN + c);
    *(float4*)(&xs[r][c]) = v;
  }
  __syncthreads();
  float acc[8] = {0.f, 0.f, 0.f, 0.f, 0.f, 0.f, 0.f, 0.f};
  const int d = tid;
#pragma unroll 8
  for (int k = 0; k < DIN; ++k) {
    float wk = W[(size_t)k * DD + d];
#pragma unroll
    for (int r = 0; r < 8; ++r) acc[r] = fmaf(xs[r][k], wk, acc[r]);
  }
  float bb = b[d];
#pragma unroll
  for (int r = 0; r < 8; ++r) {
    int row = row0 + r;
    if (row < NN) h[(size_t)row * DD + d] = fmaxf(acc[r] + bb, 0.f);
  }
}

// hn = LN(h); S[node][0..7] = {inR0,inR1,inA0,inA1,outR0,outR1,outA0,outA1}
// one wave per node
__global__ __launch_bounds__(256) void k_ln_scalars(
    const float* __restrict__ h, const float* __restrict__ ln_g, const float* __restrict__ ln_b,
    const float* __restrict__ Wir, const float* __restrict__ Wia,
    const float* __restrict__ Wor, const float* __restrict__ Woa,
    float* __restrict__ hn, float* __restrict__ S) {
  const int lane = threadIdx.x & 63;
  const int node = blockIdx.x * 4 + (threadIdx.x >> 6);
  if (node >= NN) return;
  const float4 hv = *(const float4*)(h + (size_t)node * DD + lane * 4);
  float m = waveSum(hv.x + hv.y + hv.z + hv.w) * (1.f / DD);
  float dx = hv.x - m, dy = hv.y - m, dz = hv.z - m, dw = hv.w - m;
  float var = waveSum(dx * dx + dy * dy + dz * dz + dw * dw) * (1.f / DD);
  float rs = 1.f / sqrtf(var + LN_EPS);
  const float4 g = *(const float4*)(ln_g + lane * 4);
  const float4 bb = *(const float4*)(ln_b + lane * 4);
  float4 o;
  o.x = fmaf(dx * rs, g.x, bb.x);
  o.y = fmaf(dy * rs, g.y, bb.y);
  o.z = fmaf(dz * rs, g.z, bb.z);
  o.w = fmaf(dw * rs, g.w, bb.w);
  *(float4*)(hn + (size_t)node * DD + lane * 4) = o;
  // gate-net dots: weight mats are [256,2]; lane covers rows 4*lane..4*lane+3
  float p[8];
  const float4 a0 = *(const float4*)(Wir + 8 * lane);
  const float4 a1 = *(const float4*)(Wir + 8 * lane + 4);
  p[0] = o.x * a0.x + o.y * a0.z + o.z * a1.x + o.w * a1.z;
  p[1] = o.x * a0.y + o.y * a0.w + o.z * a1.y + o.w * a1.w;
  const float4 c0 = *(const float4*)(Wia + 8 * lane);
  const float4 c1 = *(const float4*)(Wia + 8 * lane + 4);
  p[2] = o.x * c0.x + o.y * c0.z + o.z * c1.x + o.w * c1.z;
  p[3] = o.x * c0.y + o.y * c0.w + o.z * c1.y + o.w * c1.w;
  const float4 e0 = *(const float4*)(Wor + 8 * lane);
  const float4 e1 = *(const float4*)(Wor + 8 * lane + 4);
  p[4] = o.x * e0.x + o.y * e0.z + o.z * e1.x + o.w * e1.z;
  p[5] = o.x * e0.y + o.y * e0.w + o.z * e1.y + o.w * e1.w;
  const float4 f0 = *(const float4*)(Woa + 8 * lane);
  const float4 f1 = *(const float4*)(Woa + 8 * lane + 4);
  p[6] = o.x * f0.x + o.y * f0.z + o.z * f1.x + o.w * f1.z;
  p[7] = o.x * f0.y + o.y * f0.w + o.z * f1.y + o.w * f1.w;
#pragma unroll
  for (int j = 0; j < 8; ++j) p[j] = waveSum(p[j]);
  if (lane == 0) {
    *(float4*)(S + (size_t)node * 8) = make_float4(p[0], p[1], p[2], p[3]);
    *(float4*)(S + (size_t)node * 8 + 4) = make_float4(p[4], p[5], p[6], p[7]);
  }
}

// zero agg[N*256] and A[N*4] (ws is poisoned 0xAA before every call)
__global__ void k_zero(float* __restrict__ agg, float* __restrict__ A) {
  size_t i4 = ((size_t)blockIdx.x * blockDim.x + threadIdx.x) * 4;
  const size_t n_agg = (size_t)NN * DD;
  const size_t total = n_agg + (size_t)NN * 4;
  if (i4 >= total) return;
  const float4 z = make_float4(0.f, 0.f, 0.f, 0.f);
  if (i4 < n_agg) *(float4*)(agg + i4) = z;
  else *(float4*)(A + (i4 - n_agg)) = z;
}

// A[u][0..3] += {inA0,inA1,outA0,outA1}[v] per edge (scalar segment-sums)
__global__ __launch_bounds__(256) void k_scalar_agg(const int* __restrict__ ei,
                                                    const float* __restrict__ S,
                                                    float* __restrict__ A) {
  int e = blockIdx.x * 256 + threadIdx.x;
  if (e >= EE) return;
  int u = ei[e], v = ei[EE + e];
  float4 s0 = *(const float4*)(S + (size_t)v * 8);
  float4 s1 = *(const float4*)(S + (size_t)v * 8 + 4);
  float* au = A + (size_t)u * 4;
  atomicAdd(au + 0, s0.z);
  atomicAdd(au + 1, s0.w);
  atomicAdd(au + 2, s1.z);
  atomicAdd(au + 3, s1.w);
}

// hard gumbel gate = argmax(logits + g); component 0 wins ties (argmax picks index 0)
__global__ __launch_bounds__(256) void k_gates(const float* __restrict__ S, const float* __restrict__ A,
                                               const float* __restrict__ gn,
                                               const float* __restrict__ b_in, const float* __restrict__ b_out,
                                               float* __restrict__ gin, float* __restrict__ gout, int l) {
  int i = blockIdx.x * 256 + threadIdx.x;
  if (i >= NN) return;
  float4 s0 = *(const float4*)(S + (size_t)i * 8);
  float4 s1 = *(const float4*)(S + (size_t)i * 8 + 4);
  float4 a = *(const float4*)(A + (size_t)i * 4);
  const float* gi = gn + ((size_t)(l * 2 + 0) * NN + i) * 2;
  const float* go = gn + ((size_t)(l * 2 + 1) * NN + i) * 2;
  float li0 = s0.x + a.x + b_in[0] + gi[0];
  float li1 = s0.y + a.y + b_in[1] + gi[1];
  gin[i] = (li0 >= li1) ? 1.f : 0.f;
  float lo0 = s1.x + a.z + b_out[0] + go[0];
  float lo1 = s1.y + a.w + b_out[1] + go[1];
  gout[i] = (lo0 >= lo1) ? 1.f : 0.f;
}

// agg[u] += hn[v] for edges with gin[u]*gout[v]==1; one wave per edge
__global__ __launch_bounds__(256) void k_wagg(const int* __restrict__ ei,
                                              const float* __restrict__ gin, const float* __restrict__ gout,
                                              const float* __restrict__ hn, float* __restrict__ agg) {
  int e = blockIdx.x * 4 + (threadIdx.x >> 6);
  if (e >= EE) return;
  int lane = threadIdx.x & 63;
  int u = ei[e], v = ei[EE + e];
  if (gin[u] == 0.f || gout[v] == 0.f) return;
  float4 hv = *(const float4*)(hn + (size_t)v * DD + lane * 4);
  float* dst = agg + (size_t)u * DD + lane * 4;
  atomicAdd(dst + 0, hv.x);
  atomicAdd(dst + 1, hv.y);
  atomicAdd(dst + 2, hv.z);
  atomicAdd(dst + 3, hv.w);
}

// hout = relu([hn|agg] @ [Wr;Wa] + b)   K=512 fused dual GEMM, 64x64 tile
__global__ __launch_bounds__(256) void k_conv_gemm(const float* __restrict__ hn, const float* __restrict__ agg,
                                                   const float* __restrict__ Wr, const float* __restrict__ Wa,
                                                   const float* __restrict__ b, float* __restrict__ hout) {
  __shared__ float As[64][33];
  __shared__ float Bs[32][65];
  const int tid = threadIdx.x;
  const int i0 = blockIdx.x * 64;
  const int j0 = blockIdx.y * 64;
  const int tx = tid & 15, ty = tid >> 4;
  const int arow = tid >> 2, acol = (tid & 3) * 8;
  const int brow = tid >> 3, bcol = (tid & 7) * 8;
  float acc[4][4] = {{0.f}};
  for (int k0 = 0; k0 < 2 * DD; k0 += 32) {
    {
      int gr = i0 + arow;
      if (gr >= NN) gr = NN - 1;
      int gk = k0 + acol;
      const float* src = (gk < DD) ? (hn + (size_t)gr * DD + gk) : (agg + (size_t)gr * DD + (gk - DD));
      *(float4*)(&As[arow][acol]) = *(const float4*)(src);
      *(float4*)(&As[arow][acol + 4]) = *(const float4*)(src + 4);
    }
    {
      int gk = k0 + brow;
      const float* src = (gk < DD) ? (Wr + (size_t)gk * DD + j0 + bcol)
                                   : (Wa + (size_t)(gk - DD) * DD + j0 + bcol);
      *(float4*)(&Bs[brow][bcol]) = *(const float4*)(src);
      *(float4*)(&Bs[brow][bcol + 4]) = *(const float4*)(src + 4);
    }
    __syncthreads();
#pragma unroll
    for (int kk = 0; kk < 32; ++kk) {
      float av[4], bv[4];
#pragma unroll
      for (int r = 0; r < 4; ++r) av[r] = As[ty * 4 + r][kk];
#pragma unroll
      for (int c = 0; c < 4; ++c) bv[c] = Bs[kk][tx * 4 + c];
#pragma unroll
      for (int r = 0; r < 4; ++r)
#pragma unroll
        for (int c = 0; c < 4; ++c) acc[r][c] = fmaf(av[r], bv[c], acc[r][c]);
    }
    __syncthreads();
  }
  const float4 bj = *(const float4*)(b + j0 + tx * 4);
#pragma unroll
  for (int r = 0; r < 4; ++r) {
    int gr = i0 + ty * 4 + r;
    if (gr < NN) {
      float4 o;
      o.x = fmaxf(acc[r][0] + bj.x, 0.f);
      o.y = fmaxf(acc[r][1] + bj.y, 0.f);
      o.z = fmaxf(acc[r][2] + bj.z, 0.f);
      o.w = fmaxf(acc[r][3] + bj.w, 0.f);
      *(float4*)(hout + (size_t)gr * DD + j0 + tx * 4) = o;
    }
  }
}

// out = hn @ W_dec + b_dec   [N,256]@[256,64]
__global__ __launch_bounds__(256) void k_dec(const float* __restrict__ hn,
                                             const float* __restrict__ Wd, const float* __restrict__ bd,
                                             float* __restrict__ out) {
  __shared__ float As[64][33];
  __shared__ float Bs[32][65];
  const int tid = threadIdx.x;
  const int i0 = blockIdx.x * 64;
  const int tx = tid & 15, ty = tid >> 4;
  const int arow = tid >> 2, acol = (tid & 3) * 8;
  const int brow = tid >> 3, bcol = (tid & 7) * 8;
  float acc[4][4] = {{0.f}};
  for (int k0 = 0; k0 < DD; k0 += 32) {
    {
      int gr = i0 + arow;
      if (gr >= NN) gr = NN - 1;
      const float* src = hn + (size_t)gr * DD + k0 + acol;
      *(float4*)(&As[arow][acol]) = *(const float4*)(src);
      *(float4*)(&As[arow][acol + 4]) = *(const float4*)(src + 4);
    }
    {
      const float* src = Wd + (size_t)(k0 + brow) * DOUT + bcol;
      *(float4*)(&Bs[brow][bcol]) = *(const float4*)(src);
      *(float4*)(&Bs[brow][bcol + 4]) = *(const float4*)(src + 4);
    }
    __syncthreads();
#pragma unroll
    for (int kk = 0; kk < 32; ++kk) {
      float av[4], bv[4];
#pragma unroll
      for (int r = 0; r < 4; ++r) av[r] = As[ty * 4 + r][kk];
#pragma unroll
      for (int c = 0; c < 4; ++c) bv[c] = Bs[kk][tx * 4 + c];
#pragma unroll
      for (int r = 0; r < 4; ++r)
#pragma unroll
        for (int c = 0; c < 4; ++c) acc[r][c] = fmaf(av[r], bv[c], acc[r][c]);
    }
    __syncthreads();
  }
  const float4 bj = *(const float4*)(bd + tx * 4);
#pragma unroll
  for (int r = 0; r < 4; ++r) {
    int gr = i0 + ty * 4 + r;
    if (gr < NN) {
      float4 o;
      o.x = acc[r][0] + bj.x;
      o.y = acc[r][1] + bj.y;
      o.z = acc[r][2] + bj.z;
      o.w = acc[r][3] + bj.w;
      *(float4*)(out + (size_t)gr * DOUT + tx * 4) = o;
    }
  }
}

extern "C" void kernel_launch(void* const* d_in, const int* in_sizes, int n_in,
                              void* d_out, int out_size, void* d_ws, size_t ws_size,
                              hipStream_t stream) {
  const float* x = (const float*)d_in[0];
  const int* ei = (const int*)d_in[1];
  const float* gn = (const float*)d_in[2];
  const float* W_enc = (const float*)d_in[3];
  const float* b_enc = (const float*)d_in[4];
  const float* W_root = (const float*)d_in[5];
  const float* W_agg = (const float*)d_in[6];
  const float* b_env = (const float*)d_in[7];
  const float* Wa_in_r = (const float*)d_in[8];
  const float* Wa_in_a = (const float*)d_in[9];
  const float* b_in = (const float*)d_in[10];
  const float* Wa_out_r = (const float*)d_in[11];
  const float* Wa_out_a = (const float*)d_in[12];
  const float* b_out = (const float*)d_in[13];
  // d_in[14..16] (Wt_r, Wt_a, b_t) are dead in the forward pass: hard gumbel
  // output = one_hot(argmax(logits+g)), and temp>0 never changes the argmax.
  const float* ln_g = (const float*)d_in[17];
  const float* ln_b = (const float*)d_in[18];
  const float* W_dec = (const float*)d_in[19];
  const float* b_dec = (const float*)d_in[20];
  float* out = (float*)d_out;

  float* ws = (float*)d_ws;
  size_t off = 0;
  float* h = ws + off;   off += (size_t)NN * DD;
  float* hn = ws + off;  off += (size_t)NN * DD;
  float* agg = ws + off; off += (size_t)NN * DD;
  float* S = ws + off;   off += (size_t)NN * 8;
  float* A = ws + off;   off += (size_t)NN * 4;
  float* gin = ws + off; off += (size_t)NN;
  float* gout = ws + off; off += (size_t)NN;
  if (ws_size < off * sizeof(float)) return;  // insufficient scratch -> visible failure

  k_encoder<<<(NN + 7) / 8, 256, 0, stream>>>(x, W_enc, b_enc, h);

  const int zero_blocks = (int)(((size_t)NN * DD + (size_t)NN * 4) / 4 + 255) / 256;
  for (int l = 0; l < NLAYERS; ++l) {
    k_ln_scalars<<<(NN + 3) / 4, 256, 0, stream>>>(h, ln_g, ln_b, Wa_in_r, Wa_in_a,
                                                   Wa_out_r, Wa_out_a, hn, S);
    k_zero<<<zero_blocks, 256, 0, stream>>>(agg, A);
    k_scalar_agg<<<(EE + 255) / 256, 256, 0, stream>>>(ei, S, A);
    k_gates<<<(NN + 255) / 256, 256, 0, stream>>>(S, A, gn, b_in, b_out, gin, gout, l);
    k_wagg<<<(EE + 3) / 4, 256, 0, stream>>>(ei, gin, gout, hn, agg);
    k_conv_gemm<<<dim3((NN + 63) / 64, DD / 64), 256, 0, stream>>>(
        hn, agg, W_root + (size_t)l * DD * DD, W_agg + (size_t)l * DD * DD,
        b_env + (size_t)l * DD, h);
  }

  // final LN (k_ln_scalars also writes S; harmless) + decoder GEMM
  k_ln_scalars<<<(NN + 3) / 4, 256, 0, stream>>>(h, ln_g, ln_b, Wa_in_r, Wa_in_a,
                                                 Wa_out_r, Wa_out_a, hn, S);
  k_dec<<<(NN + 63) / 64, 256, 0, stream>>>(hn, W_dec, b_dec, out);
}

// Round 2
// 1560.716 us; speedup vs baseline: 2.2654x; 2.2654x over previous
//
#include <hip/hip_runtime.h>
#include <cstdint>

#define NN 50000
#define EE 800000
#define DIN 128
#define DD 256
#define DOUT 64
#define NLAYERS 3
#define LN_EPS 1e-5f

__device__ __forceinline__ float waveSum(float v) {
#pragma unroll
  for (int m = 1; m < 64; m <<= 1) v += __shfl_xor(v, m, 64);
  return v;
}

// h = relu(x @ W_enc + b_enc)   [N,128]@[128,256]
__global__ __launch_bounds__(256) void k_encoder(const float* __restrict__ x,
                                                 const float* __restrict__ W,
                                                 const float* __restrict__ b,
                                                 float* __restrict__ h) {
  __shared__ float xs[8][DIN];
  const int tid = threadIdx.x;
  const int row0 = blockIdx.x * 8;
  {
    int idx = tid * 4;
    int r = idx >> 7, c = idx & 127;
    int row = row0 + r;
    float4 v = make_float4(0.f, 0.f, 0.f, 0.f);
    if (row < NN) v = *(const float4*)(x + (size_t)row * DIN + c);
    *(float4*)(&xs[r][c]) = v;
  }
  __syncthreads();
  float acc[8] = {0.f, 0.f, 0.f, 0.f, 0.f, 0.f, 0.f, 0.f};
  const int d = tid;
#pragma unroll 8
  for (int k = 0; k < DIN; ++k) {
    float wk = W[(size_t)k * DD + d];
#pragma unroll
    for (int r = 0; r < 8; ++r) acc[r] = fmaf(xs[r][k], wk, acc[r]);
  }
  float bb = b[d];
#pragma unroll
  for (int r = 0; r < 8; ++r) {
    int row = row0 + r;
    if (row < NN) h[(size_t)row * DD + d] = fmaxf(acc[r] + bb, 0.f);
  }
}

// hn = LN(h); SR[node] = {inR0,inR1,outR0,outR1}; SA[node] = {inA0,inA1,outA0,outA1}
// one wave per node
__global__ __launch_bounds__(256) void k_ln_scalars(
    const float* __restrict__ h, const float* __restrict__ ln_g, const float* __restrict__ ln_b,
    const float* __restrict__ Wir, const float* __restrict__ Wia,
    const float* __restrict__ Wor, const float* __restrict__ Woa,
    float* __restrict__ hn, float* __restrict__ SR, float* __restrict__ SA) {
  const int lane = threadIdx.x & 63;
  const int node = blockIdx.x * 4 + (threadIdx.x >> 6);
  if (node >= NN) return;
  const float4 hv = *(const float4*)(h + (size_t)node * DD + lane * 4);
  float m = waveSum(hv.x + hv.y + hv.z + hv.w) * (1.f / DD);
  float dx = hv.x - m, dy = hv.y - m, dz = hv.z - m, dw = hv.w - m;
  float var = waveSum(dx * dx + dy * dy + dz * dz + dw * dw) * (1.f / DD);
  float rs = 1.f / sqrtf(var + LN_EPS);
  const float4 g = *(const float4*)(ln_g + lane * 4);
  const float4 bb = *(const float4*)(ln_b + lane * 4);
  float4 o;
  o.x = fmaf(dx * rs, g.x, bb.x);
  o.y = fmaf(dy * rs, g.y, bb.y);
  o.z = fmaf(dz * rs, g.z, bb.z);
  o.w = fmaf(dw * rs, g.w, bb.w);
  *(float4*)(hn + (size_t)node * DD + lane * 4) = o;
  // gate-net dots: weight mats are [256,2]; lane covers rows 4*lane..4*lane+3
  float p[8];
  const float4 a0 = *(const float4*)(Wir + 8 * lane);
  const float4 a1 = *(const float4*)(Wir + 8 * lane + 4);
  p[0] = o.x * a0.x + o.y * a0.z + o.z * a1.x + o.w * a1.z;
  p[1] = o.x * a0.y + o.y * a0.w + o.z * a1.y + o.w * a1.w;
  const float4 c0 = *(const float4*)(Wia + 8 * lane);
  const float4 c1 = *(const float4*)(Wia + 8 * lane + 4);
  p[2] = o.x * c0.x + o.y * c0.z + o.z * c1.x + o.w * c1.z;
  p[3] = o.x * c0.y + o.y * c0.w + o.z * c1.y + o.w * c1.w;
  const float4 e0 = *(const float4*)(Wor + 8 * lane);
  const float4 e1 = *(const float4*)(Wor + 8 * lane + 4);
  p[4] = o.x * e0.x + o.y * e0.z + o.z * e1.x + o.w * e1.z;
  p[5] = o.x * e0.y + o.y * e0.w + o.z * e1.y + o.w * e1.w;
  const float4 f0 = *(const float4*)(Woa + 8 * lane);
  const float4 f1 = *(const float4*)(Woa + 8 * lane + 4);
  p[6] = o.x * f0.x + o.y * f0.z + o.z * f1.x + o.w * f1.z;
  p[7] = o.x * f0.y + o.y * f0.w + o.z * f1.y + o.w * f1.w;
#pragma unroll
  for (int j = 0; j < 8; ++j) p[j] = waveSum(p[j]);
  if (lane == 0) {
    // root scalars (used at the node itself), agg scalars (gathered by in-neighbors)
    *(float4*)(SR + (size_t)node * 4) = make_float4(p[0], p[1], p[4], p[5]);
    *(float4*)(SA + (size_t)node * 4) = make_float4(p[2], p[3], p[6], p[7]);
  }
}

// ---- CSR build (edge_index is identical every call; rebuild each launch) ----
__global__ void k_zero_deg(int* __restrict__ deg) {
  int i = blockIdx.x * 256 + threadIdx.x;
  if (i < NN) deg[i] = 0;
}

__global__ void k_deg(const int* __restrict__ ei, int* __restrict__ deg) {
  int e = blockIdx.x * 256 + threadIdx.x;
  if (e < EE) atomicAdd(&deg[ei[e]], 1);
}

#define SCAN_T 1024
__global__ __launch_bounds__(SCAN_T) void k_scan(const int* __restrict__ deg,
                                                 int* __restrict__ rowptr,
                                                 int* __restrict__ cursor) {
  __shared__ int part[SCAN_T];
  const int t = threadIdx.x;
  const int CH = (NN + SCAN_T - 1) / SCAN_T;
  const int base = t * CH;
  int s = 0;
  for (int i = 0; i < CH; ++i) {
    int idx = base + i;
    if (idx < NN) s += deg[idx];
  }
  part[t] = s;
  __syncthreads();
  for (int off = 1; off < SCAN_T; off <<= 1) {
    int v = 0;
    if (t >= off) v = part[t - off];
    __syncthreads();
    if (t >= off) part[t] += v;
    __syncthreads();
  }
  int run = (t == 0) ? 0 : part[t - 1];
  for (int i = 0; i < CH; ++i) {
    int idx = base + i;
    if (idx < NN) {
      rowptr[idx] = run;
      cursor[idx] = run;
      run += deg[idx];
    }
  }
  if (t == SCAN_T - 1) rowptr[NN] = run;
}

__global__ void k_fill(const int* __restrict__ ei, int* __restrict__ cursor,
                       int* __restrict__ csr_v) {
  int e = blockIdx.x * 256 + threadIdx.x;
  if (e >= EE) return;
  int u = ei[e], v = ei[EE + e];
  int slot = atomicAdd(&cursor[u], 1);
  csr_v[slot] = v;
}

// gates: one thread per node; gather SA over in-neighbors, add root+bias+gumbel, argmax
__global__ __launch_bounds__(256) void k_gates_csr(
    const int* __restrict__ rowptr, const int* __restrict__ csr_v,
    const float* __restrict__ SR, const float* __restrict__ SA,
    const float* __restrict__ gn, const float* __restrict__ b_in,
    const float* __restrict__ b_out, float* __restrict__ gin,
    float* __restrict__ gout, int l) {
  int u = blockIdx.x * 256 + threadIdx.x;
  if (u >= NN) return;
  int beg = rowptr[u], end = rowptr[u + 1];
  float4 a = make_float4(0.f, 0.f, 0.f, 0.f);
  for (int j = beg; j < end; ++j) {
    int v = csr_v[j];
    float4 s = *(const float4*)(SA + (size_t)v * 4);
    a.x += s.x; a.y += s.y; a.z += s.z; a.w += s.w;
  }
  float4 r = *(const float4*)(SR + (size_t)u * 4);
  const float* gi = gn + ((size_t)(l * 2 + 0) * NN + u) * 2;
  const float* go = gn + ((size_t)(l * 2 + 1) * NN + u) * 2;
  float li0 = r.x + a.x + b_in[0] + gi[0];
  float li1 = r.y + a.y + b_in[1] + gi[1];
  gin[u] = (li0 >= li1) ? 1.f : 0.f;  // argmax==0 wins ties, matches jnp.argmax
  float lo0 = r.z + a.z + b_out[0] + go[0];
  float lo1 = r.w + a.w + b_out[1] + go[1];
  gout[u] = (lo0 >= lo1) ? 1.f : 0.f;
}

// agg[u] = gin[u] * sum_{v in N(u)} gout[v]*hn[v]; one wave per destination node
__global__ __launch_bounds__(256) void k_wagg_csr(
    const int* __restrict__ rowptr, const int* __restrict__ csr_v,
    const float* __restrict__ gin, const float* __restrict__ gout,
    const float* __restrict__ hn, float* __restrict__ agg) {
  const int lane = threadIdx.x & 63;
  const int u = blockIdx.x * 4 + (threadIdx.x >> 6);
  if (u >= NN) return;
  float4 acc = make_float4(0.f, 0.f, 0.f, 0.f);
  if (gin[u] != 0.f) {
    int beg = rowptr[u], end = rowptr[u + 1];
    for (int j = beg; j < end; ++j) {
      int v = csr_v[j];  // wave-uniform
      if (gout[v] != 0.f) {
        float4 hv = *(const float4*)(hn + (size_t)v * DD + lane * 4);
        acc.x += hv.x; acc.y += hv.y; acc.z += hv.z; acc.w += hv.w;
      }
    }
  }
  *(float4*)(agg + (size_t)u * DD + lane * 4) = acc;
}

// hout = relu([hn|agg] @ [Wr;Wa] + b)   K=512 fused dual GEMM, 64x64 tile
__global__ __launch_bounds__(256) void k_conv_gemm(const float* __restrict__ hn, const float* __restrict__ agg,
                                                   const float* __restrict__ Wr, const float* __restrict__ Wa,
                                                   const float* __restrict__ b, float* __restrict__ hout) {
  __shared__ float As[64][33];
  __shared__ float Bs[32][65];
  const int tid = threadIdx.x;
  const int i0 = blockIdx.x * 64;
  const int j0 = blockIdx.y * 64;
  const int tx = tid & 15, ty = tid >> 4;
  const int arow = tid >> 2, acol = (tid & 3) * 8;
  const int brow = tid >> 3, bcol = (tid & 7) * 8;
  float acc[4][4] = {{0.f}};
  for (int k0 = 0; k0 < 2 * DD; k0 += 32) {
    {
      int gr = i0 + arow;
      if (gr >= NN) gr = NN - 1;
      int gk = k0 + acol;
      const float* src = (gk < DD) ? (hn + (size_t)gr * DD + gk) : (agg + (size_t)gr * DD + (gk - DD));
      *(float4*)(&As[arow][acol]) = *(const float4*)(src);
      *(float4*)(&As[arow][acol + 4]) = *(const float4*)(src + 4);
    }
    {
      int gk = k0 + brow;
      const float* src = (gk < DD) ? (Wr + (size_t)gk * DD + j0 + bcol)
                                   : (Wa + (size_t)(gk - DD) * DD + j0 + bcol);
      *(float4*)(&Bs[brow][bcol]) = *(const float4*)(src);
      *(float4*)(&Bs[brow][bcol + 4]) = *(const float4*)(src + 4);
    }
    __syncthreads();
#pragma unroll
    for (int kk = 0; kk < 32; ++kk) {
      float av[4], bv[4];
#pragma unroll
      for (int r = 0; r < 4; ++r) av[r] = As[ty * 4 + r][kk];
#pragma unroll
      for (int c = 0; c < 4; ++c) bv[c] = Bs[kk][tx * 4 + c];
#pragma unroll
      for (int r = 0; r < 4; ++r)
#pragma unroll
        for (int c = 0; c < 4; ++c) acc[r][c] = fmaf(av[r], bv[c], acc[r][c]);
    }
    __syncthreads();
  }
  const float4 bj = *(const float4*)(b + j0 + tx * 4);
#pragma unroll
  for (int r = 0; r < 4; ++r) {
    int gr = i0 + ty * 4 + r;
    if (gr < NN) {
      float4 o;
      o.x = fmaxf(acc[r][0] + bj.x, 0.f);
      o.y = fmaxf(acc[r][1] + bj.y, 0.f);
      o.z = fmaxf(acc[r][2] + bj.z, 0.f);
      o.w = fmaxf(acc[r][3] + bj.w, 0.f);
      *(float4*)(hout + (size_t)gr * DD + j0 + tx * 4) = o;
    }
  }
}

// out = hn @ W_dec + b_dec   [N,256]@[256,64]
__global__ __launch_bounds__(256) void k_dec(const float* __restrict__ hn,
                                             const float* __restrict__ Wd, const float* __restrict__ bd,
                                             float* __restrict__ out) {
  __shared__ float As[64][33];
  __shared__ float Bs[32][65];
  const int tid = threadIdx.x;
  const int i0 = blockIdx.x * 64;
  const int tx = tid & 15, ty = tid >> 4;
  const int arow = tid >> 2, acol = (tid & 3) * 8;
  const int brow = tid >> 3, bcol = (tid & 7) * 8;
  float acc[4][4] = {{0.f}};
  for (int k0 = 0; k0 < DD; k0 += 32) {
    {
      int gr = i0 + arow;
      if (gr >= NN) gr = NN - 1;
      const float* src = hn + (size_t)gr * DD + k0 + acol;
      *(float4*)(&As[arow][acol]) = *(const float4*)(src);
      *(float4*)(&As[arow][acol + 4]) = *(const float4*)(src + 4);
    }
    {
      const float* src = Wd + (size_t)(k0 + brow) * DOUT + bcol;
      *(float4*)(&Bs[brow][bcol]) = *(const float4*)(src);
      *(float4*)(&Bs[brow][bcol + 4]) = *(const float4*)(src + 4);
    }
    __syncthreads();
#pragma unroll
    for (int kk = 0; kk < 32; ++kk) {
      float av[4], bv[4];
#pragma unroll
      for (int r = 0; r < 4; ++r) av[r] = As[ty * 4 + r][kk];
#pragma unroll
      for (int c = 0; c < 4; ++c) bv[c] = Bs[kk][tx * 4 + c];
#pragma unroll
      for (int r = 0; r < 4; ++r)
#pragma unroll
        for (int c = 0; c < 4; ++c) acc[r][c] = fmaf(av[r], bv[c], acc[r][c]);
    }
    __syncthreads();
  }
  const float4 bj = *(const float4*)(bd + tx * 4);
#pragma unroll
  for (int r = 0; r < 4; ++r) {
    int gr = i0 + ty * 4 + r;
    if (gr < NN) {
      float4 o;
      o.x = acc[r][0] + bj.x;
      o.y = acc[r][1] + bj.y;
      o.z = acc[r][2] + bj.z;
      o.w = acc[r][3] + bj.w;
      *(float4*)(out + (size_t)gr * DOUT + tx * 4) = o;
    }
  }
}

extern "C" void kernel_launch(void* const* d_in, const int* in_sizes, int n_in,
                              void* d_out, int out_size, void* d_ws, size_t ws_size,
                              hipStream_t stream) {
  const float* x = (const float*)d_in[0];
  const int* ei = (const int*)d_in[1];
  const float* gn = (const float*)d_in[2];
  const float* W_enc = (const float*)d_in[3];
  const float* b_enc = (const float*)d_in[4];
  const float* W_root = (const float*)d_in[5];
  const float* W_agg = (const float*)d_in[6];
  const float* b_env = (const float*)d_in[7];
  const float* Wa_in_r = (const float*)d_in[8];
  const float* Wa_in_a = (const float*)d_in[9];
  const float* b_in = (const float*)d_in[10];
  const float* Wa_out_r = (const float*)d_in[11];
  const float* Wa_out_a = (const float*)d_in[12];
  const float* b_out = (const float*)d_in[13];
  // d_in[14..16] (Wt_r, Wt_a, b_t) are dead in the forward pass: hard gumbel
  // output = one_hot(argmax(logits+g)), and temp>0 never changes the argmax.
  const float* ln_g = (const float*)d_in[17];
  const float* ln_b = (const float*)d_in[18];
  const float* W_dec = (const float*)d_in[19];
  const float* b_dec = (const float*)d_in[20];
  float* out = (float*)d_out;

  float* ws = (float*)d_ws;
  size_t off = 0;
  float* h = ws + off;    off += (size_t)NN * DD;
  float* hn = ws + off;   off += (size_t)NN * DD;
  float* agg = ws + off;  off += (size_t)NN * DD;
  float* SR = ws + off;   off += (size_t)NN * 4;
  float* SA = ws + off;   off += (size_t)NN * 4;
  float* gin = ws + off;  off += (size_t)NN;
  float* gout = ws + off; off += (size_t)NN;
  int* rowptr = (int*)(ws + off); off += (size_t)NN + 4;  // NN+1 used, padded
  int* csr_v = (int*)(ws + off);  off += (size_t)EE;
  if (ws_size < off * sizeof(float)) return;  // insufficient scratch -> visible failure
  // build-phase aliases (dead before gates are first written)
  int* deg = (int*)gin;
  int* cursor = (int*)gout;

  // CSR build: edge_index is constant across calls but rebuilt every launch
  k_zero_deg<<<(NN + 255) / 256, 256, 0, stream>>>(deg);
  k_deg<<<(EE + 255) / 256, 256, 0, stream>>>(ei, deg);
  k_scan<<<1, SCAN_T, 0, stream>>>(deg, rowptr, cursor);
  k_fill<<<(EE + 255) / 256, 256, 0, stream>>>(ei, cursor, csr_v);

  k_encoder<<<(NN + 7) / 8, 256, 0, stream>>>(x, W_enc, b_enc, h);

  for (int l = 0; l < NLAYERS; ++l) {
    k_ln_scalars<<<(NN + 3) / 4, 256, 0, stream>>>(h, ln_g, ln_b, Wa_in_r, Wa_in_a,
                                                   Wa_out_r, Wa_out_a, hn, SR, SA);
    k_gates_csr<<<(NN + 255) / 256, 256, 0, stream>>>(rowptr, csr_v, SR, SA, gn,
                                                      b_in, b_out, gin, gout, l);
    k_wagg_csr<<<(NN + 3) / 4, 256, 0, stream>>>(rowptr, csr_v, gin, gout, hn, agg);
    k_conv_gemm<<<dim3((NN + 63) / 64, DD / 64), 256, 0, stream>>>(
        hn, agg, W_root + (size_t)l * DD * DD, W_agg + (size_t)l * DD * DD,
        b_env + (size_t)l * DD, h);
  }

  // final LN (SR/SA writes harmless) + decoder GEMM
  k_ln_scalars<<<(NN + 3) / 4, 256, 0, stream>>>(h, ln_g, ln_b, Wa_in_r, Wa_in_a,
                                                 Wa_out_r, Wa_out_a, hn, SR, SA);
  k_dec<<<(NN + 63) / 64, 256, 0, stream>>>(hn, W_dec, b_dec, out);
}

// Round 4
// 1101.298 us; speedup vs baseline: 3.2105x; 1.4172x over previous
//
#include <hip/hip_runtime.h>
#include <cstdint>

#define NN 50000
#define EE 800000
#define DIN 128
#define DD 256
#define DOUT 64
#define NLAYERS 3
#define LN_EPS 1e-5f

typedef __attribute__((ext_vector_type(8))) unsigned short us8;
typedef __attribute__((ext_vector_type(8))) short bs8;   // bf16 MFMA fragment (4 VGPR)
typedef __attribute__((ext_vector_type(4))) float f4;    // MFMA accumulator

__device__ __forceinline__ float waveSum(float v) {
#pragma unroll
  for (int m = 1; m < 64; m <<= 1) v += __shfl_xor(v, m, 64);
  return v;
}

// 3-limb bf16 split: a = s1 + s2 + s3 + O(2^-24 |a|); each subtraction is exact.
__device__ __forceinline__ void split3(float a, unsigned short& s1, unsigned short& s2,
                                       unsigned short& s3) {
  unsigned int b = __float_as_uint(a);
  s1 = (unsigned short)(b >> 16);
  float r1 = a - __uint_as_float(b & 0xffff0000u);
  unsigned int c = __float_as_uint(r1);
  s2 = (unsigned short)(c >> 16);
  float r2 = r1 - __uint_as_float(c & 0xffff0000u);
  s3 = (unsigned short)(__float_as_uint(r2) >> 16);
}

// split 8 floats (two float4) into three us8 limbs
__device__ __forceinline__ void split8(float4 a, float4 b, us8& l1, us8& l2, us8& l3) {
  unsigned short s1, s2, s3;
  split3(a.x, s1, s2, s3); l1[0] = s1; l2[0] = s2; l3[0] = s3;
  split3(a.y, s1, s2, s3); l1[1] = s1; l2[1] = s2; l3[1] = s3;
  split3(a.z, s1, s2, s3); l1[2] = s1; l2[2] = s2; l3[2] = s3;
  split3(a.w, s1, s2, s3); l1[3] = s1; l2[3] = s2; l3[3] = s3;
  split3(b.x, s1, s2, s3); l1[4] = s1; l2[4] = s2; l3[4] = s3;
  split3(b.y, s1, s2, s3); l1[5] = s1; l2[5] = s2; l3[5] = s3;
  split3(b.z, s1, s2, s3); l1[6] = s1; l2[6] = s2; l3[6] = s3;
  split3(b.w, s1, s2, s3); l1[7] = s1; l2[7] = s2; l3[7] = s3;
}

// h = relu(x @ W_enc + b_enc)   [N,128]@[128,256]
__global__ __launch_bounds__(256) void k_encoder(const float* __restrict__ x,
                                                 const float* __restrict__ W,
                                                 const float* __restrict__ b,
                                                 float* __restrict__ h) {
  __shared__ float xs[8][DIN];
  const int tid = threadIdx.x;
  const int row0 = blockIdx.x * 8;
  {
    int idx = tid * 4;
    int r = idx >> 7, c = idx & 127;
    int row = row0 + r;
    float4 v = make_float4(0.f, 0.f, 0.f, 0.f);
    if (row < NN) v = *(const float4*)(x + (size_t)row * DIN + c);
    *(float4*)(&xs[r][c]) = v;
  }
  __syncthreads();
  float acc[8] = {0.f, 0.f, 0.f, 0.f, 0.f, 0.f, 0.f, 0.f};
  const int d = tid;
#pragma unroll 8
  for (int k = 0; k < DIN; ++k) {
    float wk = W[(size_t)k * DD + d];
#pragma unroll
    for (int r = 0; r < 8; ++r) acc[r] = fmaf(xs[r][k], wk, acc[r]);
  }
  float bb = b[d];
#pragma unroll
  for (int r = 0; r < 8; ++r) {
    int row = row0 + r;
    if (row < NN) h[(size_t)row * DD + d] = fmaxf(acc[r] + bb, 0.f);
  }
}

// hn = LN(h); SR[node]={inR0,inR1,outR0,outR1}; SA[node]={inA0,inA1,outA0,outA1}
__global__ __launch_bounds__(256) void k_ln_scalars(
    const float* __restrict__ h, const float* __restrict__ ln_g, const float* __restrict__ ln_b,
    const float* __restrict__ Wir, const float* __restrict__ Wia,
    const float* __restrict__ Wor, const float* __restrict__ Woa,
    float* __restrict__ hn, float* __restrict__ SR, float* __restrict__ SA) {
  const int lane = threadIdx.x & 63;
  const int node = blockIdx.x * 4 + (threadIdx.x >> 6);
  if (node >= NN) return;
  const float4 hv = *(const float4*)(h + (size_t)node * DD + lane * 4);
  float m = waveSum(hv.x + hv.y + hv.z + hv.w) * (1.f / DD);
  float dx = hv.x - m, dy = hv.y - m, dz = hv.z - m, dw = hv.w - m;
  float var = waveSum(dx * dx + dy * dy + dz * dz + dw * dw) * (1.f / DD);
  float rs = 1.f / sqrtf(var + LN_EPS);
  const float4 g = *(const float4*)(ln_g + lane * 4);
  const float4 bb = *(const float4*)(ln_b + lane * 4);
  float4 o;
  o.x = fmaf(dx * rs, g.x, bb.x);
  o.y = fmaf(dy * rs, g.y, bb.y);
  o.z = fmaf(dz * rs, g.z, bb.z);
  o.w = fmaf(dw * rs, g.w, bb.w);
  *(float4*)(hn + (size_t)node * DD + lane * 4) = o;
  float p[8];
  const float4 a0 = *(const float4*)(Wir + 8 * lane);
  const float4 a1 = *(const float4*)(Wir + 8 * lane + 4);
  p[0] = o.x * a0.x + o.y * a0.z + o.z * a1.x + o.w * a1.z;
  p[1] = o.x * a0.y + o.y * a0.w + o.z * a1.y + o.w * a1.w;
  const float4 c0 = *(const float4*)(Wia + 8 * lane);
  const float4 c1 = *(const float4*)(Wia + 8 * lane + 4);
  p[2] = o.x * c0.x + o.y * c0.z + o.z * c1.x + o.w * c1.z;
  p[3] = o.x * c0.y + o.y * c0.w + o.z * c1.y + o.w * c1.w;
  const float4 e0 = *(const float4*)(Wor + 8 * lane);
  const float4 e1 = *(const float4*)(Wor + 8 * lane + 4);
  p[4] = o.x * e0.x + o.y * e0.z + o.z * e1.x + o.w * e1.z;
  p[5] = o.x * e0.y + o.y * e0.w + o.z * e1.y + o.w * e1.w;
  const float4 f0 = *(const float4*)(Woa + 8 * lane);
  const float4 f1 = *(const float4*)(Woa + 8 * lane + 4);
  p[6] = o.x * f0.x + o.y * f0.z + o.z * f1.x + o.w * f1.z;
  p[7] = o.x * f0.y + o.y * f0.w + o.z * f1.y + o.w * f1.w;
#pragma unroll
  for (int j = 0; j < 8; ++j) p[j] = waveSum(p[j]);
  if (lane == 0) {
    *(float4*)(SR + (size_t)node * 4) = make_float4(p[0], p[1], p[4], p[5]);
    *(float4*)(SA + (size_t)node * 4) = make_float4(p[2], p[3], p[6], p[7]);
  }
}

// ---- CSR build (edge_index constant per call; rebuilt every launch) ----
__global__ void k_zero_deg(int* __restrict__ deg) {
  int i = blockIdx.x * 256 + threadIdx.x;
  if (i < NN) deg[i] = 0;
}

__global__ void k_deg(const int* __restrict__ ei, int* __restrict__ deg) {
  int e = blockIdx.x * 256 + threadIdx.x;
  if (e < EE) atomicAdd(&deg[ei[e]], 1);
}

#define SCAN_T 1024
__global__ __launch_bounds__(SCAN_T) void k_scan(const int* __restrict__ deg,
                                                 int* __restrict__ rowptr,
                                                 int* __restrict__ cursor) {
  __shared__ int part[SCAN_T];
  const int t = threadIdx.x;
  const int CH = (NN + SCAN_T - 1) / SCAN_T;
  const int base = t * CH;
  int s = 0;
  for (int i = 0; i < CH; ++i) {
    int idx = base + i;
    if (idx < NN) s += deg[idx];
  }
  part[t] = s;
  __syncthreads();
  for (int off = 1; off < SCAN_T; off <<= 1) {
    int v = 0;
    if (t >= off) v = part[t - off];
    __syncthreads();
    if (t >= off) part[t] += v;
    __syncthreads();
  }
  int run = (t == 0) ? 0 : part[t - 1];
  for (int i = 0; i < CH; ++i) {
    int idx = base + i;
    if (idx < NN) {
      rowptr[idx] = run;
      cursor[idx] = run;
      run += deg[idx];
    }
  }
  if (t == SCAN_T - 1) rowptr[NN] = run;
}

__global__ void k_fill(const int* __restrict__ ei, int* __restrict__ cursor,
                       int* __restrict__ csr_v) {
  int e = blockIdx.x * 256 + threadIdx.x;
  if (e >= EE) return;
  int u = ei[e], v = ei[EE + e];
  int slot = atomicAdd(&cursor[u], 1);
  csr_v[slot] = v;
}

// per-layer weight prep: WT[n][k] (k-major, K=512 = [W_root;W_agg]) -> 3 bf16 limbs
__global__ void k_prep_w3(const float* __restrict__ Wr, const float* __restrict__ Wa, int l,
                          unsigned short* __restrict__ W1, unsigned short* __restrict__ W2,
                          unsigned short* __restrict__ W3) {
  int idx = blockIdx.x * 256 + threadIdx.x;
  if (idx >= DD * 2 * DD) return;
  int n = idx >> 9;
  int k = idx & 511;
  float w = (k < DD) ? Wr[((size_t)l * DD + k) * DD + n]
                     : Wa[((size_t)l * DD + (k - DD)) * DD + n];
  unsigned short s1, s2, s3;
  split3(w, s1, s2, s3);
  W1[idx] = s1; W2[idx] = s2; W3[idx] = s3;
}

// gates: thread per node; gather SA over in-neighbors, add root+bias+gumbel, argmax
__global__ __launch_bounds__(256) void k_gates_csr(
    const int* __restrict__ rowptr, const int* __restrict__ csr_v,
    const float* __restrict__ SR, const float* __restrict__ SA,
    const float* __restrict__ gn, const float* __restrict__ b_in,
    const float* __restrict__ b_out, unsigned char* __restrict__ gin,
    unsigned char* __restrict__ gout, int l) {
  int u = blockIdx.x * 256 + threadIdx.x;
  if (u >= NN) return;
  int beg = rowptr[u], end = rowptr[u + 1];
  float4 a = make_float4(0.f, 0.f, 0.f, 0.f);
  for (int j = beg; j < end; ++j) {
    int v = csr_v[j];
    float4 s = *(const float4*)(SA + (size_t)v * 4);
    a.x += s.x; a.y += s.y; a.z += s.z; a.w += s.w;
  }
  float4 r = *(const float4*)(SR + (size_t)u * 4);
  const float* gi = gn + ((size_t)(l * 2 + 0) * NN + u) * 2;
  const float* go = gn + ((size_t)(l * 2 + 1) * NN + u) * 2;
  float li0 = r.x + a.x + b_in[0] + gi[0];
  float li1 = r.y + a.y + b_in[1] + gi[1];
  gin[u] = (li0 >= li1) ? 1 : 0;  // argmax==0 wins ties, matches jnp.argmax
  float lo0 = r.z + a.z + b_out[0] + go[0];
  float lo1 = r.w + a.w + b_out[1] + go[1];
  gout[u] = (lo0 >= lo1) ? 1 : 0;
}

// agg[u] = gin[u] * sum_{v in N(u)} gout[v]*hn[v]; one wave per destination node
__global__ __launch_bounds__(256) void k_wagg_csr(
    const int* __restrict__ rowptr, const int* __restrict__ csr_v,
    const unsigned char* __restrict__ gin, const unsigned char* __restrict__ gout,
    const float* __restrict__ hn, float* __restrict__ agg) {
  const int lane = threadIdx.x & 63;
  const int u = blockIdx.x * 4 + (threadIdx.x >> 6);
  if (u >= NN) return;
  float4 acc = make_float4(0.f, 0.f, 0.f, 0.f);
  if (gin[u]) {
    int beg = rowptr[u], end = rowptr[u + 1];
    for (int j = beg; j < end; ++j) {
      int v = csr_v[j];  // wave-uniform
      if (gout[v]) {
        float4 hv = *(const float4*)(hn + (size_t)v * DD + lane * 4);
        acc.x += hv.x; acc.y += hv.y; acc.z += hv.z; acc.w += hv.w;
      }
    }
  }
  *(float4*)(agg + (size_t)u * DD + lane * 4) = acc;
}

// hout = relu([hn|agg] @ WT^T + b) via 3-limb bf16 6-term MFMA (fp32-grade).
// 128x128 tile, BK=32, 2x2 waves of 4x4 16x16x32 fragments. LDS rows padded
// to 40 bf16 (80B stride -> 2-way bank aliasing, free per m136).
#define BM 128
#define BN 128
#define LDP 40

__global__ __launch_bounds__(256, 2) void k_conv_mfma(
    const float* __restrict__ A0,   // hn  [N][256]  (K 0..255)
    const float* __restrict__ A1,   // agg [N][256]  (K 256..511)
    const unsigned short* __restrict__ B1, const unsigned short* __restrict__ B2,
    const unsigned short* __restrict__ B3,
    const float* __restrict__ bias, float* __restrict__ hout) {
  __shared__ unsigned short lA1[BM * LDP], lA2[BM * LDP], lA3[BM * LDP];
  __shared__ unsigned short lB1[BN * LDP], lB2[BN * LDP], lB3[BN * LDP];
  const int tid = threadIdx.x;
  const int j0 = blockIdx.x * BN;
  const int i0 = blockIdx.y * BM;
  const int lane = tid & 63, w = tid >> 6;
  const int wr = w >> 1, wc = w & 1;
  const int fr = lane & 15, fs = (lane >> 4) * 8;
  const int srow = tid >> 1, sc0 = (tid & 1) * 16;
  int ga = i0 + srow;
  if (ga >= NN) ga = NN - 1;
  const size_t aoff = (size_t)ga * DD;
  const size_t boff = (size_t)(j0 + srow) * (2 * DD);
  const f4 fz = {0.f, 0.f, 0.f, 0.f};
  f4 acc[4][4];
#pragma unroll
  for (int i = 0; i < 4; ++i)
#pragma unroll
    for (int j = 0; j < 4; ++j) acc[i][j] = fz;

  float4 fa0, fa1, fa2, fa3;
  us8 rb1a, rb1b, rb2a, rb2b, rb3a, rb3b;
  {  // prefetch tile 0 (k in [0,32) -> hn side)
    const float* pa = A0 + aoff + sc0;
    fa0 = *(const float4*)(pa);      fa1 = *(const float4*)(pa + 4);
    fa2 = *(const float4*)(pa + 8);  fa3 = *(const float4*)(pa + 12);
    rb1a = *(const us8*)(B1 + boff + sc0); rb1b = *(const us8*)(B1 + boff + sc0 + 8);
    rb2a = *(const us8*)(B2 + boff + sc0); rb2b = *(const us8*)(B2 + boff + sc0 + 8);
    rb3a = *(const us8*)(B3 + boff + sc0); rb3b = *(const us8*)(B3 + boff + sc0 + 8);
  }
  for (int kt = 0; kt < 16; ++kt) {
    __syncthreads();
    {
      int o = srow * LDP + sc0;
      us8 x1, x2, x3, y1, y2, y3;
      split8(fa0, fa1, x1, x2, x3);
      split8(fa2, fa3, y1, y2, y3);
      *(us8*)&lA1[o] = x1; *(us8*)&lA1[o + 8] = y1;
      *(us8*)&lA2[o] = x2; *(us8*)&lA2[o + 8] = y2;
      *(us8*)&lA3[o] = x3; *(us8*)&lA3[o + 8] = y3;
      *(us8*)&lB1[o] = rb1a; *(us8*)&lB1[o + 8] = rb1b;
      *(us8*)&lB2[o] = rb2a; *(us8*)&lB2[o + 8] = rb2b;
      *(us8*)&lB3[o] = rb3a; *(us8*)&lB3[o + 8] = rb3b;
    }
    __syncthreads();
    if (kt < 15) {  // prefetch next tile
      int kb = (kt + 1) * 32;
      const float* abase = (kb < DD) ? A0 : A1;
      int kk = kb & (DD - 1);
      const float* pa = abase + aoff + kk + sc0;
      fa0 = *(const float4*)(pa);      fa1 = *(const float4*)(pa + 4);
      fa2 = *(const float4*)(pa + 8);  fa3 = *(const float4*)(pa + 12);
      rb1a = *(const us8*)(B1 + boff + kb + sc0); rb1b = *(const us8*)(B1 + boff + kb + sc0 + 8);
      rb2a = *(const us8*)(B2 + boff + kb + sc0); rb2b = *(const us8*)(B2 + boff + kb + sc0 + 8);
      rb3a = *(const us8*)(B3 + boff + kb + sc0); rb3b = *(const us8*)(B3 + boff + kb + sc0 + 8);
    }
    bs8 a1[4], a2[4], a3[4];
#pragma unroll
    for (int mi = 0; mi < 4; ++mi) {
      int r = (wr * 64 + mi * 16 + fr) * LDP + fs;
      a1[mi] = *(const bs8*)&lA1[r];
      a2[mi] = *(const bs8*)&lA2[r];
      a3[mi] = *(const bs8*)&lA3[r];
    }
#pragma unroll
    for (int ni = 0; ni < 4; ++ni) {
      int c = (wc * 64 + ni * 16 + fr) * LDP + fs;
      bs8 b1 = *(const bs8*)&lB1[c];
      bs8 b2 = *(const bs8*)&lB2[c];
      bs8 b3 = *(const bs8*)&lB3[c];
#pragma unroll
      for (int mi = 0; mi < 4; ++mi) {
        acc[mi][ni] = __builtin_amdgcn_mfma_f32_16x16x32_bf16(a1[mi], b1, acc[mi][ni], 0, 0, 0);
        acc[mi][ni] = __builtin_amdgcn_mfma_f32_16x16x32_bf16(a1[mi], b2, acc[mi][ni], 0, 0, 0);
        acc[mi][ni] = __builtin_amdgcn_mfma_f32_16x16x32_bf16(a2[mi], b1, acc[mi][ni], 0, 0, 0);
        acc[mi][ni] = __builtin_amdgcn_mfma_f32_16x16x32_bf16(a1[mi], b3, acc[mi][ni], 0, 0, 0);
        acc[mi][ni] = __builtin_amdgcn_mfma_f32_16x16x32_bf16(a2[mi], b2, acc[mi][ni], 0, 0, 0);
        acc[mi][ni] = __builtin_amdgcn_mfma_f32_16x16x32_bf16(a3[mi], b1, acc[mi][ni], 0, 0, 0);
      }
    }
  }
  // epilogue: C/D layout col=lane&15, row=(lane>>4)*4+r (m89-verified)
#pragma unroll
  for (int ni = 0; ni < 4; ++ni) {
    int col = j0 + wc * 64 + ni * 16 + fr;
    float bv = bias[col];
#pragma unroll
    for (int mi = 0; mi < 4; ++mi) {
      int rbase = i0 + wr * 64 + mi * 16 + (lane >> 4) * 4;
#pragma unroll
      for (int r = 0; r < 4; ++r) {
        int row = rbase + r;
        if (row < NN) hout[(size_t)row * DD + col] = fmaxf(acc[mi][ni][r] + bv, 0.f);
      }
    }
  }
}

// out = hn @ W_dec + b_dec   [N,256]@[256,64]
__global__ __launch_bounds__(256) void k_dec(const float* __restrict__ hn,
                                             const float* __restrict__ Wd, const float* __restrict__ bd,
                                             float* __restrict__ out) {
  __shared__ float As[64][33];
  __shared__ float Bs[32][65];
  const int tid = threadIdx.x;
  const int i0 = blockIdx.x * 64;
  const int tx = tid & 15, ty = tid >> 4;
  const int arow = tid >> 2, acol = (tid & 3) * 8;
  const int brow = tid >> 3, bcol = (tid & 7) * 8;
  float acc[4][4] = {{0.f}};
  for (int k0 = 0; k0 < DD; k0 += 32) {
    {
      int gr = i0 + arow;
      if (gr >= NN) gr = NN - 1;
      const float* src = hn + (size_t)gr * DD + k0 + acol;
      *(float4*)(&As[arow][acol]) = *(const float4*)(src);
      *(float4*)(&As[arow][acol + 4]) = *(const float4*)(src + 4);
    }
    {
      const float* src = Wd + (size_t)(k0 + brow) * DOUT + bcol;
      *(float4*)(&Bs[brow][bcol]) = *(const float4*)(src);
      *(float4*)(&Bs[brow][bcol + 4]) = *(const float4*)(src + 4);
    }
    __syncthreads();
#pragma unroll
    for (int kk = 0; kk < 32; ++kk) {
      float av[4], bv[4];
#pragma unroll
      for (int r = 0; r < 4; ++r) av[r] = As[ty * 4 + r][kk];
#pragma unroll
      for (int c = 0; c < 4; ++c) bv[c] = Bs[kk][tx * 4 + c];
#pragma unroll
      for (int r = 0; r < 4; ++r)
#pragma unroll
        for (int c = 0; c < 4; ++c) acc[r][c] = fmaf(av[r], bv[c], acc[r][c]);
    }
    __syncthreads();
  }
  const float4 bj = *(const float4*)(bd + tx * 4);
#pragma unroll
  for (int r = 0; r < 4; ++r) {
    int gr = i0 + ty * 4 + r;
    if (gr < NN) {
      float4 o;
      o.x = acc[r][0] + bj.x;
      o.y = acc[r][1] + bj.y;
      o.z = acc[r][2] + bj.z;
      o.w = acc[r][3] + bj.w;
      *(float4*)(out + (size_t)gr * DOUT + tx * 4) = o;
    }
  }
}

extern "C" void kernel_launch(void* const* d_in, const int* in_sizes, int n_in,
                              void* d_out, int out_size, void* d_ws, size_t ws_size,
                              hipStream_t stream) {
  const float* x = (const float*)d_in[0];
  const int* ei = (const int*)d_in[1];
  const float* gn = (const float*)d_in[2];
  const float* W_enc = (const float*)d_in[3];
  const float* b_enc = (const float*)d_in[4];
  const float* W_root = (const float*)d_in[5];
  const float* W_agg = (const float*)d_in[6];
  const float* b_env = (const float*)d_in[7];
  const float* Wa_in_r = (const float*)d_in[8];
  const float* Wa_in_a = (const float*)d_in[9];
  const float* b_in = (const float*)d_in[10];
  const float* Wa_out_r = (const float*)d_in[11];
  const float* Wa_out_a = (const float*)d_in[12];
  const float* b_out = (const float*)d_in[13];
  // d_in[14..16] (Wt_r, Wt_a, b_t) are dead: hard gumbel = one_hot(argmax(logits+g)),
  // temp>0 never changes the argmax.
  const float* ln_g = (const float*)d_in[17];
  const float* ln_b = (const float*)d_in[18];
  const float* W_dec = (const float*)d_in[19];
  const float* b_dec = (const float*)d_in[20];
  float* out = (float*)d_out;

  float* ws = (float*)d_ws;
  size_t off = 0;
  float* h = ws + off;    off += (size_t)NN * DD;
  float* hn = ws + off;   off += (size_t)NN * DD;
  float* agg = ws + off;  off += (size_t)NN * DD;
  float* SR = ws + off;   off += (size_t)NN * 4;
  float* SA = ws + off;   off += (size_t)NN * 4;
  int* rowptr = (int*)(ws + off); off += (size_t)NN + 4;
  int* csr_v = (int*)(ws + off);  off += (size_t)EE;
  unsigned char* gin = (unsigned char*)(ws + off);  off += (size_t)NN / 4;  // u8[NN]
  unsigned char* gout = (unsigned char*)(ws + off); off += (size_t)NN / 4;
  unsigned short* WT1 = (unsigned short*)(ws + off); off += (size_t)DD * 2 * DD / 2;  // per-layer limb
  unsigned short* WT2 = (unsigned short*)(ws + off); off += (size_t)DD * 2 * DD / 2;
  unsigned short* WT3 = (unsigned short*)(ws + off); off += (size_t)DD * 2 * DD / 2;
  if (ws_size < off * sizeof(float)) return;  // insufficient scratch -> visible failure
  // CSR-build aliases (SR/SA are rewritten by ln_scalars after the build)
  int* deg = (int*)SR;
  int* cursor = (int*)SA;

  k_zero_deg<<<(NN + 255) / 256, 256, 0, stream>>>(deg);
  k_deg<<<(EE + 255) / 256, 256, 0, stream>>>(ei, deg);
  k_scan<<<1, SCAN_T, 0, stream>>>(deg, rowptr, cursor);
  k_fill<<<(EE + 255) / 256, 256, 0, stream>>>(ei, cursor, csr_v);

  k_encoder<<<(NN + 7) / 8, 256, 0, stream>>>(x, W_enc, b_enc, h);

  for (int l = 0; l < NLAYERS; ++l) {
    k_ln_scalars<<<(NN + 3) / 4, 256, 0, stream>>>(h, ln_g, ln_b, Wa_in_r, Wa_in_a,
                                                   Wa_out_r, Wa_out_a, hn, SR, SA);
    k_gates_csr<<<(NN + 255) / 256, 256, 0, stream>>>(rowptr, csr_v, SR, SA, gn,
                                                      b_in, b_out, gin, gout, l);
    k_wagg_csr<<<(NN + 3) / 4, 256, 0, stream>>>(rowptr, csr_v, gin, gout, hn, agg);
    k_prep_w3<<<(DD * 2 * DD + 255) / 256, 256, 0, stream>>>(W_root, W_agg, l, WT1, WT2, WT3);
    k_conv_mfma<<<dim3(2, (NN + BM - 1) / BM), 256, 0, stream>>>(
        hn, agg, WT1, WT2, WT3, b_env + (size_t)l * DD, h);
  }

  k_ln_scalars<<<(NN + 3) / 4, 256, 0, stream>>>(h, ln_g, ln_b, Wa_in_r, Wa_in_a,
                                                 Wa_out_r, Wa_out_a, hn, SR, SA);
  k_dec<<<(NN + 63) / 64, 256, 0, stream>>>(hn, W_dec, b_dec, out);
}

// Round 5
// 919.232 us; speedup vs baseline: 3.8464x; 1.1981x over previous
//
#include <hip/hip_runtime.h>
#include <cstdint>

#define NN 50000
#define EE 800000
#define DIN 128
#define DD 256
#define DOUT 64
#define NLAYERS 3
#define LN_EPS 1e-5f
#define NB_SCAN ((NN + 255) / 256)

typedef __attribute__((ext_vector_type(8))) unsigned short us8;
typedef __attribute__((ext_vector_type(8))) short bs8;   // bf16 MFMA fragment (4 VGPR)
typedef __attribute__((ext_vector_type(4))) float f4;    // MFMA accumulator

__device__ __forceinline__ float waveSum(float v) {
#pragma unroll
  for (int m = 1; m < 64; m <<= 1) v += __shfl_xor(v, m, 64);
  return v;
}

// 3-limb bf16 split: a = s1 + s2 + s3 + O(2^-24 |a|); each subtraction is exact.
__device__ __forceinline__ void split3(float a, unsigned short& s1, unsigned short& s2,
                                       unsigned short& s3) {
  unsigned int b = __float_as_uint(a);
  s1 = (unsigned short)(b >> 16);
  float r1 = a - __uint_as_float(b & 0xffff0000u);
  unsigned int c = __float_as_uint(r1);
  s2 = (unsigned short)(c >> 16);
  float r2 = r1 - __uint_as_float(c & 0xffff0000u);
  s3 = (unsigned short)(__float_as_uint(r2) >> 16);
}

// split 8 floats (two float4) into three us8 limbs
__device__ __forceinline__ void split8(float4 a, float4 b, us8& l1, us8& l2, us8& l3) {
  unsigned short s1, s2, s3;
  split3(a.x, s1, s2, s3); l1[0] = s1; l2[0] = s2; l3[0] = s3;
  split3(a.y, s1, s2, s3); l1[1] = s1; l2[1] = s2; l3[1] = s3;
  split3(a.z, s1, s2, s3); l1[2] = s1; l2[2] = s2; l3[2] = s3;
  split3(a.w, s1, s2, s3); l1[3] = s1; l2[3] = s2; l3[3] = s3;
  split3(b.x, s1, s2, s3); l1[4] = s1; l2[4] = s2; l3[4] = s3;
  split3(b.y, s1, s2, s3); l1[5] = s1; l2[5] = s2; l3[5] = s3;
  split3(b.z, s1, s2, s3); l1[6] = s1; l2[6] = s2; l3[6] = s3;
  split3(b.w, s1, s2, s3); l1[7] = s1; l2[7] = s2; l3[7] = s3;
}

// h = relu(x @ W_enc + b_enc)   [N,128]@[128,256]
__global__ __launch_bounds__(256) void k_encoder(const float* __restrict__ x,
                                                 const float* __restrict__ W,
                                                 const float* __restrict__ b,
                                                 float* __restrict__ h) {
  __shared__ float xs[8][DIN];
  const int tid = threadIdx.x;
  const int row0 = blockIdx.x * 8;
  {
    int idx = tid * 4;
    int r = idx >> 7, c = idx & 127;
    int row = row0 + r;
    float4 v = make_float4(0.f, 0.f, 0.f, 0.f);
    if (row < NN) v = *(const float4*)(x + (size_t)row * DIN + c);
    *(float4*)(&xs[r][c]) = v;
  }
  __syncthreads();
  float acc[8] = {0.f, 0.f, 0.f, 0.f, 0.f, 0.f, 0.f, 0.f};
  const int d = tid;
#pragma unroll 8
  for (int k = 0; k < DIN; ++k) {
    float wk = W[(size_t)k * DD + d];
#pragma unroll
    for (int r = 0; r < 8; ++r) acc[r] = fmaf(xs[r][k], wk, acc[r]);
  }
  float bb = b[d];
#pragma unroll
  for (int r = 0; r < 8; ++r) {
    int row = row0 + r;
    if (row < NN) h[(size_t)row * DD + d] = fmaxf(acc[r] + bb, 0.f);
  }
}

// hn = LN(h); SR[node]={inR0,inR1,outR0,outR1}; SA[node]={inA0,inA1,outA0,outA1}
__global__ __launch_bounds__(256) void k_ln_scalars(
    const float* __restrict__ h, const float* __restrict__ ln_g, const float* __restrict__ ln_b,
    const float* __restrict__ Wir, const float* __restrict__ Wia,
    const float* __restrict__ Wor, const float* __restrict__ Woa,
    float* __restrict__ hn, float* __restrict__ SR, float* __restrict__ SA) {
  const int lane = threadIdx.x & 63;
  const int node = blockIdx.x * 4 + (threadIdx.x >> 6);
  if (node >= NN) return;
  const float4 hv = *(const float4*)(h + (size_t)node * DD + lane * 4);
  float m = waveSum(hv.x + hv.y + hv.z + hv.w) * (1.f / DD);
  float dx = hv.x - m, dy = hv.y - m, dz = hv.z - m, dw = hv.w - m;
  float var = waveSum(dx * dx + dy * dy + dz * dz + dw * dw) * (1.f / DD);
  float rs = 1.f / sqrtf(var + LN_EPS);
  const float4 g = *(const float4*)(ln_g + lane * 4);
  const float4 bb = *(const float4*)(ln_b + lane * 4);
  float4 o;
  o.x = fmaf(dx * rs, g.x, bb.x);
  o.y = fmaf(dy * rs, g.y, bb.y);
  o.z = fmaf(dz * rs, g.z, bb.z);
  o.w = fmaf(dw * rs, g.w, bb.w);
  *(float4*)(hn + (size_t)node * DD + lane * 4) = o;
  float p[8];
  const float4 a0 = *(const float4*)(Wir + 8 * lane);
  const float4 a1 = *(const float4*)(Wir + 8 * lane + 4);
  p[0] = o.x * a0.x + o.y * a0.z + o.z * a1.x + o.w * a1.z;
  p[1] = o.x * a0.y + o.y * a0.w + o.z * a1.y + o.w * a1.w;
  const float4 c0 = *(const float4*)(Wia + 8 * lane);
  const float4 c1 = *(const float4*)(Wia + 8 * lane + 4);
  p[2] = o.x * c0.x + o.y * c0.z + o.z * c1.x + o.w * c1.z;
  p[3] = o.x * c0.y + o.y * c0.w + o.z * c1.y + o.w * c1.w;
  const float4 e0 = *(const float4*)(Wor + 8 * lane);
  const float4 e1 = *(const float4*)(Wor + 8 * lane + 4);
  p[4] = o.x * e0.x + o.y * e0.z + o.z * e1.x + o.w * e1.z;
  p[5] = o.x * e0.y + o.y * e0.w + o.z * e1.y + o.w * e1.w;
  const float4 f0 = *(const float4*)(Woa + 8 * lane);
  const float4 f1 = *(const float4*)(Woa + 8 * lane + 4);
  p[6] = o.x * f0.x + o.y * f0.z + o.z * f1.x + o.w * f1.z;
  p[7] = o.x * f0.y + o.y * f0.w + o.z * f1.y + o.w * f1.w;
#pragma unroll
  for (int j = 0; j < 8; ++j) p[j] = waveSum(p[j]);
  if (lane == 0) {
    *(float4*)(SR + (size_t)node * 4) = make_float4(p[0], p[1], p[4], p[5]);
    *(float4*)(SA + (size_t)node * 4) = make_float4(p[2], p[3], p[6], p[7]);
  }
}

// ---- CSR build (edge_index constant per call; rebuilt every launch) ----
__global__ void k_zero_deg(int* __restrict__ deg) {
  int i = blockIdx.x * 256 + threadIdx.x;
  if (i < NN) deg[i] = 0;
}

__global__ void k_deg(const int* __restrict__ ei, int* __restrict__ deg) {
  int e = blockIdx.x * 256 + threadIdx.x;
  if (e < EE) atomicAdd(&deg[ei[e]], 1);
}

// 3-phase device-wide exclusive scan of deg[NN] -> rowptr/cursor (+ rowptr[NN]=E)
__global__ __launch_bounds__(256) void k_scan1(const int* __restrict__ deg,
                                               int* __restrict__ bsum) {
  __shared__ int sm[256];
  const int t = threadIdx.x;
  int i = blockIdx.x * 256 + t;
  sm[t] = (i < NN) ? deg[i] : 0;
  __syncthreads();
  for (int off = 128; off > 0; off >>= 1) {
    if (t < off) sm[t] += sm[t + off];
    __syncthreads();
  }
  if (t == 0) bsum[blockIdx.x] = sm[0];
}

__global__ __launch_bounds__(256) void k_scan2(const int* __restrict__ bsum,
                                               int* __restrict__ boff,
                                               int* __restrict__ rowptr) {
  __shared__ int sm[256];
  const int t = threadIdx.x;
  int v = (t < NB_SCAN) ? bsum[t] : 0;
  sm[t] = v;
  __syncthreads();
  for (int off = 1; off < 256; off <<= 1) {
    int x = (t >= off) ? sm[t - off] : 0;
    __syncthreads();
    sm[t] += x;
    __syncthreads();
  }
  if (t < NB_SCAN) boff[t] = sm[t] - v;  // exclusive prefix
  if (t == 0) rowptr[NN] = sm[255];      // total edge count
}

__global__ __launch_bounds__(256) void k_scan3(const int* __restrict__ deg,
                                               const int* __restrict__ boff,
                                               int* __restrict__ rowptr,
                                               int* __restrict__ cursor) {
  __shared__ int sm[256];
  const int t = threadIdx.x;
  int i = blockIdx.x * 256 + t;
  int v = (i < NN) ? deg[i] : 0;
  sm[t] = v;
  __syncthreads();
  for (int off = 1; off < 256; off <<= 1) {
    int x = (t >= off) ? sm[t - off] : 0;
    __syncthreads();
    sm[t] += x;
    __syncthreads();
  }
  if (i < NN) {
    int r = boff[blockIdx.x] + sm[t] - v;
    rowptr[i] = r;
    cursor[i] = r;
  }
}

__global__ void k_fill(const int* __restrict__ ei, int* __restrict__ cursor,
                       int* __restrict__ csr_v) {
  int e = blockIdx.x * 256 + threadIdx.x;
  if (e >= EE) return;
  int u = ei[e], v = ei[EE + e];
  int slot = atomicAdd(&cursor[u], 1);
  csr_v[slot] = v;
}

// per-layer weight prep: WT[n][k] (k-major, K=512 = [W_root;W_agg]) -> 3 bf16 limbs
__global__ void k_prep_w3(const float* __restrict__ Wr, const float* __restrict__ Wa, int l,
                          unsigned short* __restrict__ W1, unsigned short* __restrict__ W2,
                          unsigned short* __restrict__ W3) {
  int idx = blockIdx.x * 256 + threadIdx.x;
  if (idx >= DD * 2 * DD) return;
  int n = idx >> 9;
  int k = idx & 511;
  float w = (k < DD) ? Wr[((size_t)l * DD + k) * DD + n]
                     : Wa[((size_t)l * DD + (k - DD)) * DD + n];
  unsigned short s1, s2, s3;
  split3(w, s1, s2, s3);
  W1[idx] = s1; W2[idx] = s2; W3[idx] = s3;
}

// gates: thread per node; gather SA over in-neighbors, add root+bias+gumbel, argmax
__global__ __launch_bounds__(256) void k_gates_csr(
    const int* __restrict__ rowptr, const int* __restrict__ csr_v,
    const float* __restrict__ SR, const float* __restrict__ SA,
    const float* __restrict__ gn, const float* __restrict__ b_in,
    const float* __restrict__ b_out, unsigned char* __restrict__ gin,
    unsigned char* __restrict__ gout, int l) {
  int u = blockIdx.x * 256 + threadIdx.x;
  if (u >= NN) return;
  int beg = rowptr[u], end = rowptr[u + 1];
  float4 a = make_float4(0.f, 0.f, 0.f, 0.f);
  for (int j = beg; j < end; ++j) {
    int v = csr_v[j];
    float4 s = *(const float4*)(SA + (size_t)v * 4);
    a.x += s.x; a.y += s.y; a.z += s.z; a.w += s.w;
  }
  float4 r = *(const float4*)(SR + (size_t)u * 4);
  const float* gi = gn + ((size_t)(l * 2 + 0) * NN + u) * 2;
  const float* go = gn + ((size_t)(l * 2 + 1) * NN + u) * 2;
  float li0 = r.x + a.x + b_in[0] + gi[0];
  float li1 = r.y + a.y + b_in[1] + gi[1];
  gin[u] = (li0 >= li1) ? 1 : 0;  // argmax==0 wins ties, matches jnp.argmax
  float lo0 = r.z + a.z + b_out[0] + go[0];
  float lo1 = r.w + a.w + b_out[1] + go[1];
  gout[u] = (lo0 >= lo1) ? 1 : 0;
}

// agg[u] = gin[u] * sum_{v in N(u)} gout[v]*hn[v]; one wave per destination node.
// Ballot/shfl restructure: neighbor indices + gates loaded cooperatively (one
// lane each), then the passing set is walked with independent row loads (2-deep
// ILP) instead of a per-edge dependent pointer chase.
__global__ __launch_bounds__(256) void k_wagg_csr(
    const int* __restrict__ rowptr, const int* __restrict__ csr_v,
    const unsigned char* __restrict__ gin, const unsigned char* __restrict__ gout,
    const float* __restrict__ hn, float* __restrict__ agg) {
  const int lane = threadIdx.x & 63;
  const int u = blockIdx.x * 4 + (threadIdx.x >> 6);
  if (u >= NN) return;
  float4 acc = make_float4(0.f, 0.f, 0.f, 0.f);
  float4 acc2 = make_float4(0.f, 0.f, 0.f, 0.f);
  if (gin[u]) {
    int beg = rowptr[u], end = rowptr[u + 1];
    for (int j0 = beg; j0 < end; j0 += 64) {
      int rem = end - j0;
      int v = -1;
      if (lane < rem) v = csr_v[j0 + lane];
      int ok = (v >= 0) ? (int)gout[v] : 0;
      unsigned long long mask = __ballot(ok);
      while (mask) {
        int l0 = __builtin_ctzll(mask);
        mask &= mask - 1;
        int vv0 = __shfl(v, l0);
        const float4* p0 = (const float4*)(hn + (size_t)vv0 * DD + lane * 4);
        if (mask) {
          int l1 = __builtin_ctzll(mask);
          mask &= mask - 1;
          int vv1 = __shfl(v, l1);
          const float4* p1 = (const float4*)(hn + (size_t)vv1 * DD + lane * 4);
          float4 h0 = *p0;
          float4 h1 = *p1;
          acc.x += h0.x; acc.y += h0.y; acc.z += h0.z; acc.w += h0.w;
          acc2.x += h1.x; acc2.y += h1.y; acc2.z += h1.z; acc2.w += h1.w;
        } else {
          float4 h0 = *p0;
          acc.x += h0.x; acc.y += h0.y; acc.z += h0.z; acc.w += h0.w;
        }
      }
    }
    acc.x += acc2.x; acc.y += acc2.y; acc.z += acc2.z; acc.w += acc2.w;
  }
  *(float4*)(agg + (size_t)u * DD + lane * 4) = acc;
}

// hout = relu([hn|agg] @ WT^T + b) via 3-limb bf16 6-term MFMA (fp32-grade).
// 128x128 tile, BK=32, 2x2 waves of 4x4 16x16x32 fragments. LDS rows padded
// to 40 bf16 (80B stride -> 2-way bank aliasing, free per m136).
#define BM 128
#define BN 128
#define LDP 40

__global__ __launch_bounds__(256, 2) void k_conv_mfma(
    const float* __restrict__ A0,   // hn  [N][256]  (K 0..255)
    const float* __restrict__ A1,   // agg [N][256]  (K 256..511)
    const unsigned short* __restrict__ B1, const unsigned short* __restrict__ B2,
    const unsigned short* __restrict__ B3,
    const float* __restrict__ bias, float* __restrict__ hout) {
  __shared__ unsigned short lA1[BM * LDP], lA2[BM * LDP], lA3[BM * LDP];
  __shared__ unsigned short lB1[BN * LDP], lB2[BN * LDP], lB3[BN * LDP];
  const int tid = threadIdx.x;
  const int j0 = blockIdx.x * BN;
  const int i0 = blockIdx.y * BM;
  const int lane = tid & 63, w = tid >> 6;
  const int wr = w >> 1, wc = w & 1;
  const int fr = lane & 15, fs = (lane >> 4) * 8;
  const int srow = tid >> 1, sc0 = (tid & 1) * 16;
  int ga = i0 + srow;
  if (ga >= NN) ga = NN - 1;
  const size_t aoff = (size_t)ga * DD;
  const size_t boff = (size_t)(j0 + srow) * (2 * DD);
  const f4 fz = {0.f, 0.f, 0.f, 0.f};
  f4 acc[4][4];
#pragma unroll
  for (int i = 0; i < 4; ++i)
#pragma unroll
    for (int j = 0; j < 4; ++j) acc[i][j] = fz;

  float4 fa0, fa1, fa2, fa3;
  us8 rb1a, rb1b, rb2a, rb2b, rb3a, rb3b;
  {  // prefetch tile 0 (k in [0,32) -> hn side)
    const float* pa = A0 + aoff + sc0;
    fa0 = *(const float4*)(pa);      fa1 = *(const float4*)(pa + 4);
    fa2 = *(const float4*)(pa + 8);  fa3 = *(const float4*)(pa + 12);
    rb1a = *(const us8*)(B1 + boff + sc0); rb1b = *(const us8*)(B1 + boff + sc0 + 8);
    rb2a = *(const us8*)(B2 + boff + sc0); rb2b = *(const us8*)(B2 + boff + sc0 + 8);
    rb3a = *(const us8*)(B3 + boff + sc0); rb3b = *(const us8*)(B3 + boff + sc0 + 8);
  }
  for (int kt = 0; kt < 16; ++kt) {
    __syncthreads();
    {
      int o = srow * LDP + sc0;
      us8 x1, x2, x3, y1, y2, y3;
      split8(fa0, fa1, x1, x2, x3);
      split8(fa2, fa3, y1, y2, y3);
      *(us8*)&lA1[o] = x1; *(us8*)&lA1[o + 8] = y1;
      *(us8*)&lA2[o] = x2; *(us8*)&lA2[o + 8] = y2;
      *(us8*)&lA3[o] = x3; *(us8*)&lA3[o + 8] = y3;
      *(us8*)&lB1[o] = rb1a; *(us8*)&lB1[o + 8] = rb1b;
      *(us8*)&lB2[o] = rb2a; *(us8*)&lB2[o + 8] = rb2b;
      *(us8*)&lB3[o] = rb3a; *(us8*)&lB3[o + 8] = rb3b;
    }
    __syncthreads();
    if (kt < 15) {  // prefetch next tile
      int kb = (kt + 1) * 32;
      const float* abase = (kb < DD) ? A0 : A1;
      int kk = kb & (DD - 1);
      const float* pa = abase + aoff + kk + sc0;
      fa0 = *(const float4*)(pa);      fa1 = *(const float4*)(pa + 4);
      fa2 = *(const float4*)(pa + 8);  fa3 = *(const float4*)(pa + 12);
      rb1a = *(const us8*)(B1 + boff + kb + sc0); rb1b = *(const us8*)(B1 + boff + kb + sc0 + 8);
      rb2a = *(const us8*)(B2 + boff + kb + sc0); rb2b = *(const us8*)(B2 + boff + kb + sc0 + 8);
      rb3a = *(const us8*)(B3 + boff + kb + sc0); rb3b = *(const us8*)(B3 + boff + kb + sc0 + 8);
    }
    bs8 a1[4], a2[4], a3[4];
#pragma unroll
    for (int mi = 0; mi < 4; ++mi) {
      int r = (wr * 64 + mi * 16 + fr) * LDP + fs;
      a1[mi] = *(const bs8*)&lA1[r];
      a2[mi] = *(const bs8*)&lA2[r];
      a3[mi] = *(const bs8*)&lA3[r];
    }
#pragma unroll
    for (int ni = 0; ni < 4; ++ni) {
      int c = (wc * 64 + ni * 16 + fr) * LDP + fs;
      bs8 b1 = *(const bs8*)&lB1[c];
      bs8 b2 = *(const bs8*)&lB2[c];
      bs8 b3 = *(const bs8*)&lB3[c];
#pragma unroll
      for (int mi = 0; mi < 4; ++mi) {
        acc[mi][ni] = __builtin_amdgcn_mfma_f32_16x16x32_bf16(a1[mi], b1, acc[mi][ni], 0, 0, 0);
        acc[mi][ni] = __builtin_amdgcn_mfma_f32_16x16x32_bf16(a1[mi], b2, acc[mi][ni], 0, 0, 0);
        acc[mi][ni] = __builtin_amdgcn_mfma_f32_16x16x32_bf16(a2[mi], b1, acc[mi][ni], 0, 0, 0);
        acc[mi][ni] = __builtin_amdgcn_mfma_f32_16x16x32_bf16(a1[mi], b3, acc[mi][ni], 0, 0, 0);
        acc[mi][ni] = __builtin_amdgcn_mfma_f32_16x16x32_bf16(a2[mi], b2, acc[mi][ni], 0, 0, 0);
        acc[mi][ni] = __builtin_amdgcn_mfma_f32_16x16x32_bf16(a3[mi], b1, acc[mi][ni], 0, 0, 0);
      }
    }
  }
  // epilogue: C/D layout col=lane&15, row=(lane>>4)*4+r (m89-verified)
#pragma unroll
  for (int ni = 0; ni < 4; ++ni) {
    int col = j0 + wc * 64 + ni * 16 + fr;
    float bv = bias[col];
#pragma unroll
    for (int mi = 0; mi < 4; ++mi) {
      int rbase = i0 + wr * 64 + mi * 16 + (lane >> 4) * 4;
#pragma unroll
      for (int r = 0; r < 4; ++r) {
        int row = rbase + r;
        if (row < NN) hout[(size_t)row * DD + col] = fmaxf(acc[mi][ni][r] + bv, 0.f);
      }
    }
  }
}

// out = hn @ W_dec + b_dec   [N,256]@[256,64]
__global__ __launch_bounds__(256) void k_dec(const float* __restrict__ hn,
                                             const float* __restrict__ Wd, const float* __restrict__ bd,
                                             float* __restrict__ out) {
  __shared__ float As[64][33];
  __shared__ float Bs[32][65];
  const int tid = threadIdx.x;
  const int i0 = blockIdx.x * 64;
  const int tx = tid & 15, ty = tid >> 4;
  const int arow = tid >> 2, acol = (tid & 3) * 8;
  const int brow = tid >> 3, bcol = (tid & 7) * 8;
  float acc[4][4] = {{0.f}};
  for (int k0 = 0; k0 < DD; k0 += 32) {
    {
      int gr = i0 + arow;
      if (gr >= NN) gr = NN - 1;
      const float* src = hn + (size_t)gr * DD + k0 + acol;
      *(float4*)(&As[arow][acol]) = *(const float4*)(src);
      *(float4*)(&As[arow][acol + 4]) = *(const float4*)(src + 4);
    }
    {
      const float* src = Wd + (size_t)(k0 + brow) * DOUT + bcol;
      *(float4*)(&Bs[brow][bcol]) = *(const float4*)(src);
      *(float4*)(&Bs[brow][bcol + 4]) = *(const float4*)(src + 4);
    }
    __syncthreads();
#pragma unroll
    for (int kk = 0; kk < 32; ++kk) {
      float av[4], bv[4];
#pragma unroll
      for (int r = 0; r < 4; ++r) av[r] = As[ty * 4 + r][kk];
#pragma unroll
      for (int c = 0; c < 4; ++c) bv[c] = Bs[kk][tx * 4 + c];
#pragma unroll
      for (int r = 0; r < 4; ++r)
#pragma unroll
        for (int c = 0; c < 4; ++c) acc[r][c] = fmaf(av[r], bv[c], acc[r][c]);
    }
    __syncthreads();
  }
  const float4 bj = *(const float4*)(bd + tx * 4);
#pragma unroll
  for (int r = 0; r < 4; ++r) {
    int gr = i0 + ty * 4 + r;
    if (gr < NN) {
      float4 o;
      o.x = acc[r][0] + bj.x;
      o.y = acc[r][1] + bj.y;
      o.z = acc[r][2] + bj.z;
      o.w = acc[r][3] + bj.w;
      *(float4*)(out + (size_t)gr * DOUT + tx * 4) = o;
    }
  }
}

extern "C" void kernel_launch(void* const* d_in, const int* in_sizes, int n_in,
                              void* d_out, int out_size, void* d_ws, size_t ws_size,
                              hipStream_t stream) {
  const float* x = (const float*)d_in[0];
  const int* ei = (const int*)d_in[1];
  const float* gn = (const float*)d_in[2];
  const float* W_enc = (const float*)d_in[3];
  const float* b_enc = (const float*)d_in[4];
  const float* W_root = (const float*)d_in[5];
  const float* W_agg = (const float*)d_in[6];
  const float* b_env = (const float*)d_in[7];
  const float* Wa_in_r = (const float*)d_in[8];
  const float* Wa_in_a = (const float*)d_in[9];
  const float* b_in = (const float*)d_in[10];
  const float* Wa_out_r = (const float*)d_in[11];
  const float* Wa_out_a = (const float*)d_in[12];
  const float* b_out = (const float*)d_in[13];
  // d_in[14..16] (Wt_r, Wt_a, b_t) are dead: hard gumbel = one_hot(argmax(logits+g)),
  // temp>0 never changes the argmax.
  const float* ln_g = (const float*)d_in[17];
  const float* ln_b = (const float*)d_in[18];
  const float* W_dec = (const float*)d_in[19];
  const float* b_dec = (const float*)d_in[20];
  float* out = (float*)d_out;

  float* ws = (float*)d_ws;
  size_t off = 0;
  float* h = ws + off;    off += (size_t)NN * DD;
  float* hn = ws + off;   off += (size_t)NN * DD;
  float* agg = ws + off;  off += (size_t)NN * DD;
  float* SR = ws + off;   off += (size_t)NN * 4;
  float* SA = ws + off;   off += (size_t)NN * 4;
  int* rowptr = (int*)(ws + off); off += (size_t)NN + 4;
  int* csr_v = (int*)(ws + off);  off += (size_t)EE;
  unsigned char* gin = (unsigned char*)(ws + off);  off += (size_t)NN / 4;  // u8[NN]
  unsigned char* gout = (unsigned char*)(ws + off); off += (size_t)NN / 4;
  unsigned short* WT1 = (unsigned short*)(ws + off); off += (size_t)DD * 2 * DD / 2;  // per-layer limb
  unsigned short* WT2 = (unsigned short*)(ws + off); off += (size_t)DD * 2 * DD / 2;
  unsigned short* WT3 = (unsigned short*)(ws + off); off += (size_t)DD * 2 * DD / 2;
  if (ws_size < off * sizeof(float)) return;  // insufficient scratch -> visible failure
  // CSR-build aliases (SR/SA are 4*NN ints each; rewritten by ln_scalars later)
  int* deg = (int*)SR;
  int* bsum = (int*)SR + NN;        // 256 ints, within SR's 4*NN
  int* boff = (int*)SR + NN + 256;  // 256 ints
  int* cursor = (int*)SA;

  k_zero_deg<<<(NN + 255) / 256, 256, 0, stream>>>(deg);
  k_deg<<<(EE + 255) / 256, 256, 0, stream>>>(ei, deg);
  k_scan1<<<NB_SCAN, 256, 0, stream>>>(deg, bsum);
  k_scan2<<<1, 256, 0, stream>>>(bsum, boff, rowptr);
  k_scan3<<<NB_SCAN, 256, 0, stream>>>(deg, boff, rowptr, cursor);
  k_fill<<<(EE + 255) / 256, 256, 0, stream>>>(ei, cursor, csr_v);

  k_encoder<<<(NN + 7) / 8, 256, 0, stream>>>(x, W_enc, b_enc, h);

  for (int l = 0; l < NLAYERS; ++l) {
    k_ln_scalars<<<(NN + 3) / 4, 256, 0, stream>>>(h, ln_g, ln_b, Wa_in_r, Wa_in_a,
                                                   Wa_out_r, Wa_out_a, hn, SR, SA);
    k_gates_csr<<<(NN + 255) / 256, 256, 0, stream>>>(rowptr, csr_v, SR, SA, gn,
                                                      b_in, b_out, gin, gout, l);
    k_wagg_csr<<<(NN + 3) / 4, 256, 0, stream>>>(rowptr, csr_v, gin, gout, hn, agg);
    k_prep_w3<<<(DD * 2 * DD + 255) / 256, 256, 0, stream>>>(W_root, W_agg, l, WT1, WT2, WT3);
    k_conv_mfma<<<dim3(2, (NN + BM - 1) / BM), 256, 0, stream>>>(
        hn, agg, WT1, WT2, WT3, b_env + (size_t)l * DD, h);
  }

  k_ln_scalars<<<(NN + 3) / 4, 256, 0, stream>>>(h, ln_g, ln_b, Wa_in_r, Wa_in_a,
                                                 Wa_out_r, Wa_out_a, hn, SR, SA);
  k_dec<<<(NN + 63) / 64, 256, 0, stream>>>(hn, W_dec, b_dec, out);
}

// Round 6
// 737.515 us; speedup vs baseline: 4.7941x; 1.2464x over previous
//
#include <hip/hip_runtime.h>
#include <cstdint>

#define NN 50000
#define EE 800000
#define DIN 128
#define DD 256
#define DOUT 64
#define NLAYERS 3
#define LN_EPS 1e-5f
#define NB_SCAN ((NN + 255) / 256)

typedef __attribute__((ext_vector_type(8))) _Float16 h8;  // fp16 MFMA fragment (4 VGPR)
typedef __attribute__((ext_vector_type(4))) float f4;     // MFMA accumulator

__device__ __forceinline__ float waveSum(float v) {
#pragma unroll
  for (int m = 1; m < 64; m <<= 1) v += __shfl_xor(v, m, 64);
  return v;
}

// fp16 2-limb split: a = h1 + h2 + O(2^-22 |a|); each product h*h' is exact in fp32
// (11-bit x 11-bit mantissas), so a 3-term MFMA reconstruction is fp32-grade.
__device__ __forceinline__ void splith(const float4& a, const float4& b, h8& p1, h8& p2) {
  float t[8] = {a.x, a.y, a.z, a.w, b.x, b.y, b.z, b.w};
#pragma unroll
  for (int i = 0; i < 8; ++i) {
    _Float16 x = (_Float16)t[i];
    p1[i] = x;
    p2[i] = (_Float16)(t[i] - (float)x);
  }
}

// hn = LN(h); SR[node]={inR0,inR1,outR0,outR1}; SA[node]={inA0,inA1,outA0,outA1}
__global__ __launch_bounds__(256) void k_ln_scalars(
    const float* __restrict__ h, const float* __restrict__ ln_g, const float* __restrict__ ln_b,
    const float* __restrict__ Wir, const float* __restrict__ Wia,
    const float* __restrict__ Wor, const float* __restrict__ Woa,
    float* __restrict__ hn, float* __restrict__ SR, float* __restrict__ SA) {
  const int lane = threadIdx.x & 63;
  const int node = blockIdx.x * 4 + (threadIdx.x >> 6);
  if (node >= NN) return;
  const float4 hv = *(const float4*)(h + (size_t)node * DD + lane * 4);
  float m = waveSum(hv.x + hv.y + hv.z + hv.w) * (1.f / DD);
  float dx = hv.x - m, dy = hv.y - m, dz = hv.z - m, dw = hv.w - m;
  float var = waveSum(dx * dx + dy * dy + dz * dz + dw * dw) * (1.f / DD);
  float rs = 1.f / sqrtf(var + LN_EPS);
  const float4 g = *(const float4*)(ln_g + lane * 4);
  const float4 bb = *(const float4*)(ln_b + lane * 4);
  float4 o;
  o.x = fmaf(dx * rs, g.x, bb.x);
  o.y = fmaf(dy * rs, g.y, bb.y);
  o.z = fmaf(dz * rs, g.z, bb.z);
  o.w = fmaf(dw * rs, g.w, bb.w);
  *(float4*)(hn + (size_t)node * DD + lane * 4) = o;
  float p[8];
  const float4 a0 = *(const float4*)(Wir + 8 * lane);
  const float4 a1 = *(const float4*)(Wir + 8 * lane + 4);
  p[0] = o.x * a0.x + o.y * a0.z + o.z * a1.x + o.w * a1.z;
  p[1] = o.x * a0.y + o.y * a0.w + o.z * a1.y + o.w * a1.w;
  const float4 c0 = *(const float4*)(Wia + 8 * lane);
  const float4 c1 = *(const float4*)(Wia + 8 * lane + 4);
  p[2] = o.x * c0.x + o.y * c0.z + o.z * c1.x + o.w * c1.z;
  p[3] = o.x * c0.y + o.y * c0.w + o.z * c1.y + o.w * c1.w;
  const float4 e0 = *(const float4*)(Wor + 8 * lane);
  const float4 e1 = *(const float4*)(Wor + 8 * lane + 4);
  p[4] = o.x * e0.x + o.y * e0.z + o.z * e1.x + o.w * e1.z;
  p[5] = o.x * e0.y + o.y * e0.w + o.z * e1.y + o.w * e1.w;
  const float4 f0 = *(const float4*)(Woa + 8 * lane);
  const float4 f1 = *(const float4*)(Woa + 8 * lane + 4);
  p[6] = o.x * f0.x + o.y * f0.z + o.z * f1.x + o.w * f1.z;
  p[7] = o.x * f0.y + o.y * f0.w + o.z * f1.y + o.w * f1.w;
#pragma unroll
  for (int j = 0; j < 8; ++j) p[j] = waveSum(p[j]);
  if (lane == 0) {
    *(float4*)(SR + (size_t)node * 4) = make_float4(p[0], p[1], p[4], p[5]);
    *(float4*)(SA + (size_t)node * 4) = make_float4(p[2], p[3], p[6], p[7]);
  }
}

// ---- CSR build (edge_index constant per call; rebuilt every launch) ----
__global__ void k_zero_deg(int* __restrict__ deg) {
  int i = blockIdx.x * 256 + threadIdx.x;
  if (i < NN) deg[i] = 0;
}

__global__ void k_deg(const int* __restrict__ ei, int* __restrict__ deg) {
  int e = blockIdx.x * 256 + threadIdx.x;
  if (e < EE) atomicAdd(&deg[ei[e]], 1);
}

// 3-phase device-wide exclusive scan of deg[NN] -> rowptr/cursor (+ rowptr[NN]=E)
__global__ __launch_bounds__(256) void k_scan1(const int* __restrict__ deg,
                                               int* __restrict__ bsum) {
  __shared__ int sm[256];
  const int t = threadIdx.x;
  int i = blockIdx.x * 256 + t;
  sm[t] = (i < NN) ? deg[i] : 0;
  __syncthreads();
  for (int off = 128; off > 0; off >>= 1) {
    if (t < off) sm[t] += sm[t + off];
    __syncthreads();
  }
  if (t == 0) bsum[blockIdx.x] = sm[0];
}

__global__ __launch_bounds__(256) void k_scan2(const int* __restrict__ bsum,
                                               int* __restrict__ boff,
                                               int* __restrict__ rowptr) {
  __shared__ int sm[256];
  const int t = threadIdx.x;
  int v = (t < NB_SCAN) ? bsum[t] : 0;
  sm[t] = v;
  __syncthreads();
  for (int off = 1; off < 256; off <<= 1) {
    int x = (t >= off) ? sm[t - off] : 0;
    __syncthreads();
    sm[t] += x;
    __syncthreads();
  }
  if (t < NB_SCAN) boff[t] = sm[t] - v;  // exclusive prefix
  if (t == 0) rowptr[NN] = sm[255];      // total edge count
}

__global__ __launch_bounds__(256) void k_scan3(const int* __restrict__ deg,
                                               const int* __restrict__ boff,
                                               int* __restrict__ rowptr,
                                               int* __restrict__ cursor) {
  __shared__ int sm[256];
  const int t = threadIdx.x;
  int i = blockIdx.x * 256 + t;
  int v = (i < NN) ? deg[i] : 0;
  sm[t] = v;
  __syncthreads();
  for (int off = 1; off < 256; off <<= 1) {
    int x = (t >= off) ? sm[t - off] : 0;
    __syncthreads();
    sm[t] += x;
    __syncthreads();
  }
  if (i < NN) {
    int r = boff[blockIdx.x] + sm[t] - v;
    rowptr[i] = r;
    cursor[i] = r;
  }
}

__global__ void k_fill(const int* __restrict__ ei, int* __restrict__ cursor,
                       int* __restrict__ csr_v) {
  int e = blockIdx.x * 256 + threadIdx.x;
  if (e >= EE) return;
  int u = ei[e], v = ei[EE + e];
  int slot = atomicAdd(&cursor[u], 1);
  csr_v[slot] = v;
}

// generic weight prep: W[K][N] (row-major) -> WT limbs [N][K] fp16 h1/h2
__global__ void k_prep_generic(const float* __restrict__ W, int K, int N,
                               _Float16* __restrict__ W1, _Float16* __restrict__ W2) {
  int idx = blockIdx.x * 256 + threadIdx.x;
  if (idx >= K * N) return;
  int n = idx / K, k = idx - n * K;
  float w = W[(size_t)k * N + n];
  _Float16 x = (_Float16)w;
  W1[idx] = x;
  W2[idx] = (_Float16)(w - (float)x);
}

// conv weight prep: [W_root;W_agg] K=512 -> WT limbs [256][512]
__global__ void k_prep_conv(const float* __restrict__ Wr, const float* __restrict__ Wa, int l,
                            _Float16* __restrict__ W1, _Float16* __restrict__ W2) {
  int idx = blockIdx.x * 256 + threadIdx.x;
  if (idx >= DD * 2 * DD) return;
  int n = idx >> 9, k = idx & 511;
  float w = (k < DD) ? Wr[((size_t)l * DD + k) * DD + n]
                     : Wa[((size_t)l * DD + (k - DD)) * DD + n];
  _Float16 x = (_Float16)w;
  W1[idx] = x;
  W2[idx] = (_Float16)(w - (float)x);
}

// gates: thread per node; gather SA over in-neighbors, add root+bias+gumbel, argmax
__global__ __launch_bounds__(256) void k_gates_csr(
    const int* __restrict__ rowptr, const int* __restrict__ csr_v,
    const float* __restrict__ SR, const float* __restrict__ SA,
    const float* __restrict__ gn, const float* __restrict__ b_in,
    const float* __restrict__ b_out, unsigned char* __restrict__ gin,
    unsigned char* __restrict__ gout, int l) {
  int u = blockIdx.x * 256 + threadIdx.x;
  if (u >= NN) return;
  int beg = rowptr[u], end = rowptr[u + 1];
  float4 a = make_float4(0.f, 0.f, 0.f, 0.f);
  for (int j = beg; j < end; ++j) {
    int v = csr_v[j];
    float4 s = *(const float4*)(SA + (size_t)v * 4);
    a.x += s.x; a.y += s.y; a.z += s.z; a.w += s.w;
  }
  float4 r = *(const float4*)(SR + (size_t)u * 4);
  const float* gi = gn + ((size_t)(l * 2 + 0) * NN + u) * 2;
  const float* go = gn + ((size_t)(l * 2 + 1) * NN + u) * 2;
  float li0 = r.x + a.x + b_in[0] + gi[0];
  float li1 = r.y + a.y + b_in[1] + gi[1];
  gin[u] = (li0 >= li1) ? 1 : 0;  // argmax==0 wins ties, matches jnp.argmax
  float lo0 = r.z + a.z + b_out[0] + go[0];
  float lo1 = r.w + a.w + b_out[1] + go[1];
  gout[u] = (lo0 >= lo1) ? 1 : 0;
}

// agg[u] = gin[u] * sum_{v in N(u)} gout[v]*hn[v]; one wave per destination node.
__global__ __launch_bounds__(256) void k_wagg_csr(
    const int* __restrict__ rowptr, const int* __restrict__ csr_v,
    const unsigned char* __restrict__ gin, const unsigned char* __restrict__ gout,
    const float* __restrict__ hn, float* __restrict__ agg) {
  const int lane = threadIdx.x & 63;
  const int u = blockIdx.x * 4 + (threadIdx.x >> 6);
  if (u >= NN) return;
  float4 acc = make_float4(0.f, 0.f, 0.f, 0.f);
  float4 acc2 = make_float4(0.f, 0.f, 0.f, 0.f);
  if (gin[u]) {
    int beg = rowptr[u], end = rowptr[u + 1];
    for (int j0 = beg; j0 < end; j0 += 64) {
      int rem = end - j0;
      int v = -1;
      if (lane < rem) v = csr_v[j0 + lane];
      int ok = (v >= 0) ? (int)gout[v] : 0;
      unsigned long long mask = __ballot(ok);
      while (mask) {
        int l0 = __builtin_ctzll(mask);
        mask &= mask - 1;
        int vv0 = __shfl(v, l0);
        const float4* p0 = (const float4*)(hn + (size_t)vv0 * DD + lane * 4);
        if (mask) {
          int l1 = __builtin_ctzll(mask);
          mask &= mask - 1;
          int vv1 = __shfl(v, l1);
          const float4* p1 = (const float4*)(hn + (size_t)vv1 * DD + lane * 4);
          float4 h0 = *p0;
          float4 h1 = *p1;
          acc.x += h0.x; acc.y += h0.y; acc.z += h0.z; acc.w += h0.w;
          acc2.x += h1.x; acc2.y += h1.y; acc2.z += h1.z; acc2.w += h1.w;
        } else {
          float4 h0 = *p0;
          acc.x += h0.x; acc.y += h0.y; acc.z += h0.z; acc.w += h0.w;
        }
      }
    }
    acc.x += acc2.x; acc.y += acc2.y; acc.z += acc2.z; acc.w += acc2.w;
  }
  *(float4*)(agg + (size_t)u * DD + lane * 4) = acc;
}

// Generic fp16-2-limb 3-term MFMA GEMM: outp = [relu](A @ B^T + bias)
// A fp32 (split in-register during staging), B pre-split fp16 limbs [N][K].
// BM=128 rows/block; BN = NFN*32 cols (waves 2x2, NFN 16-col frags per wave).
#define BM 128
#define LDP 40  // halves; 80B row stride (2-way bank aliasing base pattern)

template <int KTOT, int ASTR, int NFN, int OSTR, bool RELU, bool DUAL>
__global__ __launch_bounds__(256, 4) void k_mfma_gemm(
    const float* __restrict__ A0, const float* __restrict__ A1,
    const _Float16* __restrict__ B1, const _Float16* __restrict__ B2,
    const float* __restrict__ bias, float* __restrict__ outp) {
  constexpr int BN = NFN * 32;
  constexpr int KSTEPS = KTOT / 32;
  __shared__ _Float16 lA1[BM * LDP], lA2[BM * LDP];
  __shared__ _Float16 lB1[BN * LDP], lB2[BN * LDP];
  const int tid = threadIdx.x;
  const int j0 = blockIdx.x * BN;
  const int i0 = blockIdx.y * BM;
  const int lane = tid & 63, w = tid >> 6;
  const int wr = w >> 1, wc = w & 1;
  const int fr = lane & 15, fs = (lane >> 4) * 8;
  const int asr = tid >> 1, asc = (tid & 1) * 16;  // A staging: 16 floats/thread
  int ga = i0 + asr;
  if (ga >= NN) ga = NN - 1;
  const int bsr = (BN == 128) ? (tid >> 1) : (tid >> 2);
  const int bsc = (BN == 128) ? ((tid & 1) * 16) : ((tid & 3) * 8);
  const size_t boff = (size_t)(j0 + bsr) * KTOT + bsc;

  f4 acc[4][NFN];
#pragma unroll
  for (int i = 0; i < 4; ++i)
#pragma unroll
    for (int j = 0; j < NFN; ++j) acc[i][j] = (f4){0.f, 0.f, 0.f, 0.f};

  float4 fa0, fa1, fa2, fa3;
  h8 rb1a, rb1b, rb2a, rb2b;
  {  // prefetch K-tile 0
    const float* pa;
    if constexpr (DUAL) pa = A0 + (size_t)ga * DD + asc;
    else pa = A0 + (size_t)ga * ASTR + asc;
    fa0 = *(const float4*)(pa);     fa1 = *(const float4*)(pa + 4);
    fa2 = *(const float4*)(pa + 8); fa3 = *(const float4*)(pa + 12);
    rb1a = *(const h8*)(B1 + boff);
    rb2a = *(const h8*)(B2 + boff);
    if constexpr (BN == 128) {
      rb1b = *(const h8*)(B1 + boff + 8);
      rb2b = *(const h8*)(B2 + boff + 8);
    }
  }
  for (int kt = 0; kt < KSTEPS; ++kt) {
    __syncthreads();
    {
      int o = asr * LDP + asc;
      h8 p1a, p1b, p2a, p2b;
      splith(fa0, fa1, p1a, p2a);
      splith(fa2, fa3, p1b, p2b);
      *(h8*)&lA1[o] = p1a; *(h8*)&lA1[o + 8] = p1b;
      *(h8*)&lA2[o] = p2a; *(h8*)&lA2[o + 8] = p2b;
      int ob = bsr * LDP + bsc;
      *(h8*)&lB1[ob] = rb1a;
      *(h8*)&lB2[ob] = rb2a;
      if constexpr (BN == 128) {
        *(h8*)&lB1[ob + 8] = rb1b;
        *(h8*)&lB2[ob + 8] = rb2b;
      }
    }
    __syncthreads();
    if (kt < KSTEPS - 1) {  // prefetch next K-tile
      int kb = (kt + 1) * 32;
      const float* pa;
      if constexpr (DUAL) {
        const float* ab = (kb < DD) ? A0 : A1;
        pa = ab + (size_t)ga * DD + (kb & (DD - 1)) + asc;
      } else {
        pa = A0 + (size_t)ga * ASTR + kb + asc;
      }
      fa0 = *(const float4*)(pa);     fa1 = *(const float4*)(pa + 4);
      fa2 = *(const float4*)(pa + 8); fa3 = *(const float4*)(pa + 12);
      rb1a = *(const h8*)(B1 + boff + kb);
      rb2a = *(const h8*)(B2 + boff + kb);
      if constexpr (BN == 128) {
        rb1b = *(const h8*)(B1 + boff + kb + 8);
        rb2b = *(const h8*)(B2 + boff + kb + 8);
      }
    }
    h8 a1[4], a2[4];
#pragma unroll
    for (int mi = 0; mi < 4; ++mi) {
      int r = (wr * 64 + mi * 16 + fr) * LDP + fs;
      a1[mi] = *(const h8*)&lA1[r];
      a2[mi] = *(const h8*)&lA2[r];
    }
#pragma unroll
    for (int ni = 0; ni < NFN; ++ni) {
      int c = (wc * (NFN * 16) + ni * 16 + fr) * LDP + fs;
      h8 b1 = *(const h8*)&lB1[c];
      h8 b2 = *(const h8*)&lB2[c];
#pragma unroll
      for (int mi = 0; mi < 4; ++mi) {
        acc[mi][ni] = __builtin_amdgcn_mfma_f32_16x16x32_f16(a1[mi], b1, acc[mi][ni], 0, 0, 0);
        acc[mi][ni] = __builtin_amdgcn_mfma_f32_16x16x32_f16(a1[mi], b2, acc[mi][ni], 0, 0, 0);
        acc[mi][ni] = __builtin_amdgcn_mfma_f32_16x16x32_f16(a2[mi], b1, acc[mi][ni], 0, 0, 0);
      }
    }
  }
  // epilogue: C/D layout col=lane&15, row=(lane>>4)*4+r (m89-verified)
#pragma unroll
  for (int ni = 0; ni < NFN; ++ni) {
    int col = j0 + wc * (NFN * 16) + ni * 16 + fr;
    float bv = bias[col];
#pragma unroll
    for (int mi = 0; mi < 4; ++mi) {
      int rbase = i0 + wr * 64 + mi * 16 + (lane >> 4) * 4;
#pragma unroll
      for (int r = 0; r < 4; ++r) {
        int row = rbase + r;
        if (row < NN) {
          float v = acc[mi][ni][r] + bv;
          outp[(size_t)row * OSTR + col] = RELU ? fmaxf(v, 0.f) : v;
        }
      }
    }
  }
}

extern "C" void kernel_launch(void* const* d_in, const int* in_sizes, int n_in,
                              void* d_out, int out_size, void* d_ws, size_t ws_size,
                              hipStream_t stream) {
  const float* x = (const float*)d_in[0];
  const int* ei = (const int*)d_in[1];
  const float* gn = (const float*)d_in[2];
  const float* W_enc = (const float*)d_in[3];
  const float* b_enc = (const float*)d_in[4];
  const float* W_root = (const float*)d_in[5];
  const float* W_agg = (const float*)d_in[6];
  const float* b_env = (const float*)d_in[7];
  const float* Wa_in_r = (const float*)d_in[8];
  const float* Wa_in_a = (const float*)d_in[9];
  const float* b_in = (const float*)d_in[10];
  const float* Wa_out_r = (const float*)d_in[11];
  const float* Wa_out_a = (const float*)d_in[12];
  const float* b_out = (const float*)d_in[13];
  // d_in[14..16] (Wt_r, Wt_a, b_t) are dead: hard gumbel = one_hot(argmax(logits+g)),
  // temp>0 never changes the argmax.
  const float* ln_g = (const float*)d_in[17];
  const float* ln_b = (const float*)d_in[18];
  const float* W_dec = (const float*)d_in[19];
  const float* b_dec = (const float*)d_in[20];
  float* out = (float*)d_out;

  float* ws = (float*)d_ws;
  size_t off = 0;
  float* h = ws + off;    off += (size_t)NN * DD;
  float* hn = ws + off;   off += (size_t)NN * DD;
  float* agg = ws + off;  off += (size_t)NN * DD;
  float* SR = ws + off;   off += (size_t)NN * 4;
  float* SA = ws + off;   off += (size_t)NN * 4;
  int* rowptr = (int*)(ws + off); off += (size_t)NN + 4;
  int* csr_v = (int*)(ws + off);  off += (size_t)EE;
  unsigned char* gin = (unsigned char*)(ws + off);  off += (size_t)NN / 4;  // u8[NN]
  unsigned char* gout = (unsigned char*)(ws + off); off += (size_t)NN / 4;
  _Float16* cW1 = (_Float16*)(ws + off); off += (size_t)DD * 2 * DD / 2;  // [256][512]
  _Float16* cW2 = (_Float16*)(ws + off); off += (size_t)DD * 2 * DD / 2;
  _Float16* eW1 = (_Float16*)(ws + off); off += (size_t)DD * DIN / 2;     // [256][128]
  _Float16* eW2 = (_Float16*)(ws + off); off += (size_t)DD * DIN / 2;
  _Float16* dW1 = (_Float16*)(ws + off); off += (size_t)DOUT * DD / 2;    // [64][256]
  _Float16* dW2 = (_Float16*)(ws + off); off += (size_t)DOUT * DD / 2;
  if (ws_size < off * sizeof(float)) return;  // insufficient scratch -> visible failure
  // CSR-build aliases (SR/SA are 4*NN ints each; rewritten by ln_scalars later)
  int* deg = (int*)SR;
  int* bsum = (int*)SR + NN;        // 256 ints, within SR's 4*NN
  int* boff = (int*)SR + NN + 256;  // 256 ints
  int* cursor = (int*)SA;

  k_zero_deg<<<(NN + 255) / 256, 256, 0, stream>>>(deg);
  k_deg<<<(EE + 255) / 256, 256, 0, stream>>>(ei, deg);
  k_scan1<<<NB_SCAN, 256, 0, stream>>>(deg, bsum);
  k_scan2<<<1, 256, 0, stream>>>(bsum, boff, rowptr);
  k_scan3<<<NB_SCAN, 256, 0, stream>>>(deg, boff, rowptr, cursor);
  k_fill<<<(EE + 255) / 256, 256, 0, stream>>>(ei, cursor, csr_v);

  k_prep_generic<<<(DIN * DD + 255) / 256, 256, 0, stream>>>(W_enc, DIN, DD, eW1, eW2);
  k_prep_generic<<<(DD * DOUT + 255) / 256, 256, 0, stream>>>(W_dec, DD, DOUT, dW1, dW2);

  const int gy = (NN + BM - 1) / BM;
  // encoder: h = relu(x @ W_enc + b_enc)
  k_mfma_gemm<DIN, DIN, 4, DD, true, false><<<dim3(2, gy), 256, 0, stream>>>(
      x, nullptr, eW1, eW2, b_enc, h);

  for (int l = 0; l < NLAYERS; ++l) {
    k_ln_scalars<<<(NN + 3) / 4, 256, 0, stream>>>(h, ln_g, ln_b, Wa_in_r, Wa_in_a,
                                                   Wa_out_r, Wa_out_a, hn, SR, SA);
    k_gates_csr<<<(NN + 255) / 256, 256, 0, stream>>>(rowptr, csr_v, SR, SA, gn,
                                                      b_in, b_out, gin, gout, l);
    k_wagg_csr<<<(NN + 3) / 4, 256, 0, stream>>>(rowptr, csr_v, gin, gout, hn, agg);
    k_prep_conv<<<(DD * 2 * DD + 255) / 256, 256, 0, stream>>>(W_root, W_agg, l, cW1, cW2);
    // conv: h = relu([hn|agg] @ [Wr;Wa] + b_env)
    k_mfma_gemm<2 * DD, DD, 4, DD, true, true><<<dim3(2, gy), 256, 0, stream>>>(
        hn, agg, cW1, cW2, b_env + (size_t)l * DD, h);
  }

  k_ln_scalars<<<(NN + 3) / 4, 256, 0, stream>>>(h, ln_g, ln_b, Wa_in_r, Wa_in_a,
                                                 Wa_out_r, Wa_out_a, hn, SR, SA);
  // decoder: out = hn @ W_dec + b_dec
  k_mfma_gemm<DD, DD, 2, DOUT, false, false><<<dim3(1, gy), 256, 0, stream>>>(
      hn, nullptr, dW1, dW2, b_dec, out);
}